// Round 1
// baseline (1147.831 us; speedup 1.0000x reference)
//
#include <hip/hip_runtime.h>
#include <hip/hip_bf16.h>
#include <math.h>

// CHRONOS inference: GEMMs + 3x GAT (CSR segment softmax) + classifier.
// Round 1: fp32 vector GEMM baseline, bf16 storage only for hW3 (164MB->82MB).

#define HID 256
#define HEADS 8
#define FIN 235

__device__ __forceinline__ float elu_f(float x) { return x > 0.f ? x : expm1f(x); }

// ---------------- CSR build ----------------
__global__ void init_deg_k(int* __restrict__ deg, int* __restrict__ fillc, int n) {
  int i = blockIdx.x * blockDim.x + threadIdx.x;
  if (i < n) { deg[i] = 1; fillc[i] = 0; }  // deg=1 accounts for self-loop
}

__global__ void count_k(const int* __restrict__ ei, int* __restrict__ deg, int E) {
  int i = blockIdx.x * blockDim.x + threadIdx.x;
  if (i < E) atomicAdd(&deg[ei[E + i]], 1);  // dst row = ei[E..2E)
}

__global__ void scan_k(const int* __restrict__ deg, int* __restrict__ rp, int n) {
  __shared__ int sm[1024];
  __shared__ int s_carry;
  int tid = threadIdx.x;
  if (tid == 0) s_carry = 0;
  __syncthreads();
  for (int base = 0; base < n; base += 1024) {
    int i = base + tid;
    int v = (i < n) ? deg[i] : 0;
    sm[tid] = v;
    __syncthreads();
    for (int off = 1; off < 1024; off <<= 1) {
      int t = (tid >= off) ? sm[tid - off] : 0;
      __syncthreads();
      sm[tid] += t;
      __syncthreads();
    }
    int carry = s_carry;
    if (i < n) rp[i + 1] = carry + sm[tid];
    __syncthreads();
    if (tid == 1023) s_carry = carry + sm[1023];
    __syncthreads();
  }
  if (tid == 0) rp[0] = 0;
}

__global__ void fill_k(const int* __restrict__ ei, const int* __restrict__ rp,
                       int* __restrict__ fillc, int* __restrict__ colA, int E, int n) {
  int i = blockIdx.x * blockDim.x + threadIdx.x;
  if (i < E) {
    int d = ei[E + i];
    int pos = rp[d] + atomicAdd(&fillc[d], 1);
    colA[pos] = ei[i];
  } else if (i < E + n) {
    int v = i - E;
    int pos = rp[v] + atomicAdd(&fillc[v], 1);
    colA[pos] = v;  // self-loop
  }
}

// ---------------- fp32 tiled GEMM: C = act(A@B + bias) ----------------
// 64x64 tile, 256 threads, 4x4 micro-tile, TK=16. ACT: 0=none 1=relu 2=elu.
template <int ACT, int BF16OUT>
__global__ __launch_bounds__(256) void gemm_k(
    const float* __restrict__ A, int lda, const float* __restrict__ B, int ldb,
    const float* __restrict__ bias, float* __restrict__ Cf,
    __hip_bfloat16* __restrict__ Cb, int ldc, int M, int N, int K) {
  __shared__ float As[16][65];  // [k][m], padded: staging writes 4-way-conflict-free
  __shared__ float Bs[16][64];  // [k][n]
  int tid = threadIdx.x;
  int tx = tid & 15, ty = tid >> 4;
  int row0 = blockIdx.y * 64, col0 = blockIdx.x * 64;
  float acc[4][4] = {};
  int am = tid >> 2;         // 0..63
  int ak = (tid & 3) << 2;   // 0,4,8,12
  int bk = tid >> 4;         // 0..15
  int bn = (tid & 15) << 2;  // 0..60
  const float* Arow = A + (size_t)(row0 + am) * lda;
  bool aok = (row0 + am) < M;
  const float* Bp = B + col0 + bn;
  for (int k0 = 0; k0 < K; k0 += 16) {
    __syncthreads();
#pragma unroll
    for (int j = 0; j < 4; j++) {
      int kk = k0 + ak + j;
      As[ak + j][am] = (aok && kk < K) ? Arow[kk] : 0.f;
    }
    {
      int kk = k0 + bk;
      float4 bv = make_float4(0.f, 0.f, 0.f, 0.f);
      if (kk < K) bv = *reinterpret_cast<const float4*>(Bp + (size_t)kk * ldb);
      *reinterpret_cast<float4*>(&Bs[bk][bn]) = bv;
    }
    __syncthreads();
#pragma unroll
    for (int k = 0; k < 16; k++) {
      float4 b = *reinterpret_cast<const float4*>(&Bs[k][tx << 2]);
      float a0 = As[k][(ty << 2) + 0];
      float a1 = As[k][(ty << 2) + 1];
      float a2 = As[k][(ty << 2) + 2];
      float a3 = As[k][(ty << 2) + 3];
      acc[0][0] += a0 * b.x; acc[0][1] += a0 * b.y; acc[0][2] += a0 * b.z; acc[0][3] += a0 * b.w;
      acc[1][0] += a1 * b.x; acc[1][1] += a1 * b.y; acc[1][2] += a1 * b.z; acc[1][3] += a1 * b.w;
      acc[2][0] += a2 * b.x; acc[2][1] += a2 * b.y; acc[2][2] += a2 * b.z; acc[2][3] += a2 * b.w;
      acc[3][0] += a3 * b.x; acc[3][1] += a3 * b.y; acc[3][2] += a3 * b.z; acc[3][3] += a3 * b.w;
    }
  }
#pragma unroll
  for (int i = 0; i < 4; i++) {
    int r = row0 + (ty << 2) + i;
    if (r >= M) continue;
#pragma unroll
    for (int j = 0; j < 4; j++) {
      int c = col0 + (tx << 2) + j;
      if (c >= N) continue;
      float v = acc[i][j];
      if (bias) v += bias[c];
      if (ACT == 1) v = fmaxf(v, 0.f);
      if (ACT == 2) v = elu_f(v);
      if (BF16OUT) Cb[(size_t)r * ldc + c] = __float2bfloat16(v);
      else Cf[(size_t)r * ldc + c] = v;
    }
  }
}

// ---------------- GAT alpha: per-(node,head) dot of hW row with a_src/a_dst ----------------
__global__ void alpha_small_k(const float* __restrict__ hW, const float* __restrict__ a_s,
                              const float* __restrict__ a_d, float* __restrict__ as_,
                              float* __restrict__ ad_, int M) {
  int idx = blockIdx.x * blockDim.x + threadIdx.x;
  if (idx >= M * HEADS) return;
  int h = idx & 7;
  const float* row = hW + (size_t)(idx >> 3) * HID + h * 32;
  const float* ws = a_s + h * 32;
  const float* wd = a_d + h * 32;
  float s = 0.f, d = 0.f;
#pragma unroll
  for (int c = 0; c < 32; c++) { float v = row[c]; s += v * ws[c]; d += v * wd[c]; }
  as_[idx] = s;
  ad_[idx] = d;
}

__global__ void alpha_big_k(const __hip_bfloat16* __restrict__ hW, const float* __restrict__ a_s,
                            const float* __restrict__ a_d, float* __restrict__ as_,
                            float* __restrict__ ad_, int M) {
  int idx = blockIdx.x * blockDim.x + threadIdx.x;
  if (idx >= M * HEADS) return;
  int h = idx & 7;
  const __hip_bfloat16* row = hW + (size_t)(idx >> 3) * 2048 + h * 256;
  const float* ws = a_s + h * 256;
  const float* wd = a_d + h * 256;
  float s = 0.f, d = 0.f;
  for (int c = 0; c < 256; c++) {
    float v = __bfloat162float(row[c]);
    s += v * ws[c];
    d += v * wd[c];
  }
  as_[idx] = s;
  ad_[idx] = d;
}

// ---------------- GAT aggregate (C=32 layers): fused segment softmax + gather + bias + elu ----
// one 64-thread block per dst; thread t owns channels 4t..4t+3 (head t/8).
__global__ __launch_bounds__(64) void agg_small_k(
    const int* __restrict__ rp, const int* __restrict__ col, const float* __restrict__ hW,
    const float* __restrict__ as_, const float* __restrict__ ad_,
    const float* __restrict__ bias, float* __restrict__ out) {
  int dst = blockIdx.x;
  int t = threadIdx.x;
  int h = t >> 3;
  int c = t << 2;
  int beg = rp[dst], end = rp[dst + 1];
  float adv = ad_[dst * 8 + h];
  float m = -3.4e38f;
  for (int i = beg; i < end; i++) {
    int s = col[i];
    float e = as_[s * 8 + h] + adv;
    e = e > 0.f ? e : 0.2f * e;
    m = fmaxf(m, e);
  }
  float den = 0.f;
  float4 acc = make_float4(0.f, 0.f, 0.f, 0.f);
  for (int i = beg; i < end; i++) {
    int s = col[i];
    float e = as_[s * 8 + h] + adv;
    e = e > 0.f ? e : 0.2f * e;
    float ex = __expf(e - m);
    den += ex;
    float4 hv = *reinterpret_cast<const float4*>(hW + (size_t)s * HID + c);
    acc.x += ex * hv.x; acc.y += ex * hv.y; acc.z += ex * hv.z; acc.w += ex * hv.w;
  }
  float inv = 1.f / (den + 1e-16f);
  float4 bv = *reinterpret_cast<const float4*>(bias + c);
  float4 r;
  r.x = elu_f(acc.x * inv + bv.x);
  r.y = elu_f(acc.y * inv + bv.y);
  r.z = elu_f(acc.z * inv + bv.z);
  r.w = elu_f(acc.w * inv + bv.w);
  *reinterpret_cast<float4*>(out + (size_t)dst * HID + c) = r;
}

// ---------------- GAT layer-3 aggregate (C=256) + bias + elu + head-mean -> comb[:,0:256] ----
// one 256-thread block per dst; thread t owns channel t of every head.
__global__ __launch_bounds__(256) void agg_big_k(
    const int* __restrict__ rp, const int* __restrict__ col,
    const __hip_bfloat16* __restrict__ hW, const float* __restrict__ as_,
    const float* __restrict__ ad_, const float* __restrict__ bias,
    float* __restrict__ comb) {
  int dst = blockIdx.x;
  int t = threadIdx.x;
  int beg = rp[dst], end = rp[dst + 1];
  float adv[8], m[8], den[8], acc[8];
#pragma unroll
  for (int h = 0; h < 8; h++) {
    adv[h] = ad_[dst * 8 + h];
    m[h] = -3.4e38f;
    den[h] = 0.f;
    acc[h] = 0.f;
  }
  for (int i = beg; i < end; i++) {
    int s = col[i];
#pragma unroll
    for (int h = 0; h < 8; h++) {
      float e = as_[s * 8 + h] + adv[h];
      e = e > 0.f ? e : 0.2f * e;
      m[h] = fmaxf(m[h], e);
    }
  }
  for (int i = beg; i < end; i++) {
    int s = col[i];
    const __hip_bfloat16* hrow = hW + (size_t)s * 2048 + t;
#pragma unroll
    for (int h = 0; h < 8; h++) {
      float e = as_[s * 8 + h] + adv[h];
      e = e > 0.f ? e : 0.2f * e;
      float ex = __expf(e - m[h]);
      den[h] += ex;
      acc[h] += ex * __bfloat162float(hrow[h * 256]);
    }
  }
  float g = 0.f;
#pragma unroll
  for (int h = 0; h < 8; h++) {
    float v = acc[h] / (den[h] + 1e-16f) + bias[h * 256 + t];
    g += elu_f(v);
  }
  comb[(size_t)dst * 512 + t] = g * 0.125f;
}

// ---------------- final: logits = hidden @ w_c2 + b_c2 (one wave per node) ----------------
__global__ __launch_bounds__(64) void final_k(const float* __restrict__ hidden,
                                              const float* __restrict__ w,
                                              const float* __restrict__ b,
                                              float* __restrict__ out) {
  int n = blockIdx.x;
  int l = threadIdx.x;
  const float* hr = hidden + (size_t)n * HID;
  float a0 = 0.f, a1 = 0.f;
  for (int k = l; k < HID; k += 64) {
    float hv = hr[k];
    a0 += hv * w[k * 2 + 0];
    a1 += hv * w[k * 2 + 1];
  }
  for (int off = 32; off > 0; off >>= 1) {
    a0 += __shfl_down(a0, off);
    a1 += __shfl_down(a1, off);
  }
  if (l == 0) {
    out[n * 2 + 0] = a0 + b[0];
    out[n * 2 + 1] = a1 + b[1];
  }
}

extern "C" void kernel_launch(void* const* d_in, const int* in_sizes, int n_in,
                              void* d_out, int out_size, void* d_ws, size_t ws_size,
                              hipStream_t stream) {
  const float* x      = (const float*)d_in[0];
  const int*   ei     = (const int*)d_in[1];
  const float* w_in   = (const float*)d_in[2];
  const float* b_in   = (const float*)d_in[3];
  const float* w_t1   = (const float*)d_in[4];
  const float* b_t1   = (const float*)d_in[5];
  const float* w_t2   = (const float*)d_in[6];
  const float* b_t2   = (const float*)d_in[7];
  const float* w_g1   = (const float*)d_in[8];
  const float* a_src1 = (const float*)d_in[9];
  const float* a_dst1 = (const float*)d_in[10];
  const float* b_g1   = (const float*)d_in[11];
  const float* w_g2   = (const float*)d_in[12];
  const float* a_src2 = (const float*)d_in[13];
  const float* a_dst2 = (const float*)d_in[14];
  const float* b_g2   = (const float*)d_in[15];
  const float* w_g3   = (const float*)d_in[16];
  const float* a_src3 = (const float*)d_in[17];
  const float* a_dst3 = (const float*)d_in[18];
  const float* b_g3   = (const float*)d_in[19];
  const float* w_c1   = (const float*)d_in[20];
  const float* b_c1   = (const float*)d_in[21];
  const float* w_c2   = (const float*)d_in[22];
  const float* b_c2   = (const float*)d_in[23];
  const int M = in_sizes[0] / FIN;  // 20000
  const int E = in_sizes[1] / 2;    // 120000
  (void)n_in; (void)out_size; (void)ws_size;

  char* wsb = (char*)d_ws;
  size_t off = 0;
  auto alloc = [&](size_t bytes) {
    void* p = wsb + off;
    off = (off + bytes + 255) & ~(size_t)255;
    return p;
  };
  float* bufA = (float*)alloc((size_t)M * HID * 4);       // h, later g2
  float* bufB = (float*)alloc((size_t)M * HID * 4);       // th, later g1
  float* comb = (float*)alloc((size_t)M * 2 * HID * 4);   // [g | t]
  void* hWreg = alloc((size_t)M * 2048 * 2);              // bf16 [M,2048]; also f32 [M,256] scratch
  float* hWf = (float*)hWreg;
  __hip_bfloat16* hWb = (__hip_bfloat16*)hWreg;
  float* as_ = (float*)alloc((size_t)M * 8 * 4);
  float* ad_ = (float*)alloc((size_t)M * 8 * 4);
  int* deg   = (int*)alloc((size_t)M * 4);
  int* fillc = (int*)alloc((size_t)M * 4);
  int* rp    = (int*)alloc((size_t)(M + 1) * 4);
  int* colA  = (int*)alloc((size_t)(E + M) * 4);

  // ---- CSR build (by dst, with self-loops) ----
  init_deg_k<<<(M + 255) / 256, 256, 0, stream>>>(deg, fillc, M);
  count_k<<<(E + 255) / 256, 256, 0, stream>>>(ei, deg, E);
  scan_k<<<1, 1024, 0, stream>>>(deg, rp, M);
  fill_k<<<(E + M + 255) / 256, 256, 0, stream>>>(ei, rp, fillc, colA, E, M);

  auto gemm = [&](const float* A, int lda, const float* B, int ldb, const float* bias,
                  float* Cf, __hip_bfloat16* Cb, int ldc, int m, int n, int k, int act) {
    dim3 g((n + 63) / 64, (m + 63) / 64);
    if (Cb)
      gemm_k<0, 1><<<g, 256, 0, stream>>>(A, lda, B, ldb, bias, nullptr, Cb, ldc, m, n, k);
    else if (act == 0)
      gemm_k<0, 0><<<g, 256, 0, stream>>>(A, lda, B, ldb, bias, Cf, nullptr, ldc, m, n, k);
    else if (act == 1)
      gemm_k<1, 0><<<g, 256, 0, stream>>>(A, lda, B, ldb, bias, Cf, nullptr, ldc, m, n, k);
    else
      gemm_k<2, 0><<<g, 256, 0, stream>>>(A, lda, B, ldb, bias, Cf, nullptr, ldc, m, n, k);
  };

  // h = elu(x @ w_in + b_in)
  gemm(x, FIN, w_in, HID, b_in, bufA, nullptr, HID, M, HID, FIN, 2);
  // th = relu(h @ w_t1 + b_t1)
  gemm(bufA, HID, w_t1, HID, b_t1, bufB, nullptr, HID, M, HID, HID, 1);
  // t = th @ w_t2 + b_t2  -> comb[:, 256:512]
  gemm(bufB, HID, w_t2, HID, b_t2, comb + HID, nullptr, 2 * HID, M, HID, HID, 0);

  // ---- GAT 1 ----
  gemm(bufA, HID, w_g1, HID, nullptr, hWf, nullptr, HID, M, HID, HID, 0);
  alpha_small_k<<<(M * 8 + 63) / 64, 64, 0, stream>>>(hWf, a_src1, a_dst1, as_, ad_, M);
  agg_small_k<<<M, 64, 0, stream>>>(rp, colA, hWf, as_, ad_, b_g1, bufB);  // g1

  // ---- GAT 2 ----
  gemm(bufB, HID, w_g2, HID, nullptr, hWf, nullptr, HID, M, HID, HID, 0);
  alpha_small_k<<<(M * 8 + 63) / 64, 64, 0, stream>>>(hWf, a_src2, a_dst2, as_, ad_, M);
  agg_small_k<<<M, 64, 0, stream>>>(rp, colA, hWf, as_, ad_, b_g2, bufA);  // g2

  // ---- GAT 3 (wide): hW3 bf16, fused agg+bias+elu+head-mean -> comb[:,0:256] ----
  gemm(bufA, HID, w_g3, 2048, nullptr, nullptr, hWb, 2048, M, 2048, HID, 0);
  alpha_big_k<<<(M * 8 + 63) / 64, 64, 0, stream>>>(hWb, a_src3, a_dst3, as_, ad_, M);
  agg_big_k<<<M, 256, 0, stream>>>(rp, colA, hWb, as_, ad_, b_g3, comb);

  // ---- classifier ----
  gemm(comb, 2 * HID, w_c1, HID, b_c1, hWf, nullptr, HID, M, HID, 2 * HID, 1);  // hidden (reuse hW region)
  final_k<<<M, 64, 0, stream>>>(hWf, w_c2, b_c2, (float*)d_out);
}

// Round 2
// 601.024 us; speedup vs baseline: 1.9098x; 1.9098x over previous
//
#include <hip/hip_runtime.h>
#include <hip/hip_bf16.h>
#include <math.h>

// CHRONOS inference. Round 2: all GEMMs on bf16 MFMA 16x16x32 (128x128 tile,
// BK=32, 4 waves x 4x4 frags, LDS rows padded to 40 shorts -> conflict-free),
// bf16 activations end-to-end, fp32 accumulate. Weights transposed+cast once
// per launch; x cast/padded to K=256.

#define HID 256
#define HEADS 8
#define FIN 235

typedef __attribute__((ext_vector_type(8))) short short8;
typedef __attribute__((ext_vector_type(4))) float floatx4;

__device__ __forceinline__ float elu_f(float x) { return x > 0.f ? x : expm1f(x); }
__device__ __forceinline__ float bf2f(unsigned short u) {
  return __uint_as_float(((unsigned int)u) << 16);
}
__device__ __forceinline__ unsigned short f2bf(float f) {
  union { __hip_bfloat16 b; unsigned short u; } c;
  c.b = __float2bfloat16(f);
  return c.u;
}

// ---------------- conversions ----------------
__global__ void xcvt_k(const float* __restrict__ x, __hip_bfloat16* __restrict__ xb, int M) {
  int id = blockIdx.x * blockDim.x + threadIdx.x;
  if (id >= M * 256) return;
  int m = id >> 8, k = id & 255;
  xb[id] = (k < FIN) ? __float2bfloat16(x[(size_t)m * FIN + k]) : __float2bfloat16(0.f);
}

// wt[n*Kpad + k] = w[k*N + n] (bf16), zero-padded for k in [K, Kpad)
__global__ void tcvt_k(const float* __restrict__ w, __hip_bfloat16* __restrict__ wt,
                       int K, int Kpad, int N) {
  __shared__ float t[32][33];
  int nb = blockIdx.x * 32, kb = blockIdx.y * 32;
  int tx = threadIdx.x, ty = threadIdx.y;
#pragma unroll
  for (int j = 0; j < 32; j += 8) {
    int k = kb + ty + j;
    t[ty + j][tx] = (k < K) ? w[(size_t)k * N + nb + tx] : 0.f;
  }
  __syncthreads();
#pragma unroll
  for (int j = 0; j < 32; j += 8) {
    int n = nb + ty + j;
    int k = kb + tx;
    wt[(size_t)n * Kpad + k] = __float2bfloat16(t[tx][ty + j]);
  }
}

// ---------------- CSR build ----------------
__global__ void init_deg_k(int* __restrict__ deg, int* __restrict__ fillc, int n) {
  int i = blockIdx.x * blockDim.x + threadIdx.x;
  if (i < n) { deg[i] = 1; fillc[i] = 0; }  // deg=1 accounts for self-loop
}

__global__ void count_k(const int* __restrict__ ei, int* __restrict__ deg, int E) {
  int i = blockIdx.x * blockDim.x + threadIdx.x;
  if (i < E) atomicAdd(&deg[ei[E + i]], 1);
}

__global__ void scan_k(const int* __restrict__ deg, int* __restrict__ rp, int n) {
  __shared__ int wsum[16];
  __shared__ int s_carry;
  int tid = threadIdx.x, lane = tid & 63, wid = tid >> 6;
  if (tid == 0) { s_carry = 0; rp[0] = 0; }
  __syncthreads();
  for (int base = 0; base < n; base += 1024) {
    int i = base + tid;
    int x = (i < n) ? deg[i] : 0;
#pragma unroll
    for (int off = 1; off < 64; off <<= 1) {
      int y = __shfl_up(x, off);
      if (lane >= off) x += y;
    }
    if (lane == 63) wsum[wid] = x;
    __syncthreads();
    if (wid == 0 && lane < 16) {
      int s = wsum[lane];
#pragma unroll
      for (int off = 1; off < 16; off <<= 1) {
        int y = __shfl_up(s, off);
        if (lane >= off) s += y;
      }
      wsum[lane] = s;
    }
    __syncthreads();
    int offset = s_carry + (wid > 0 ? wsum[wid - 1] : 0);
    if (i < n) rp[i + 1] = offset + x;
    __syncthreads();
    if (tid == 1023) s_carry += wsum[15];
    __syncthreads();
  }
}

__global__ void fill_k(const int* __restrict__ ei, const int* __restrict__ rp,
                       int* __restrict__ fillc, int* __restrict__ colA, int E, int n) {
  int i = blockIdx.x * blockDim.x + threadIdx.x;
  if (i < E) {
    int d = ei[E + i];
    int pos = rp[d] + atomicAdd(&fillc[d], 1);
    colA[pos] = ei[i];
  } else if (i < E + n) {
    int v = i - E;
    int pos = rp[v] + atomicAdd(&fillc[v], 1);
    colA[pos] = v;
  }
}

// ---------------- bf16 MFMA GEMM: C = act(A @ Bt^T + bias) ----------------
// A [M,K] bf16 row-major, Bt [N,K] bf16 row-major. 128x128 tile, BK=32,
// 256 threads = 4 waves, each wave 64x64 via 4x4 mfma_16x16x32 frags.
// LDS rows padded to 40 shorts (80B): staging b128 writes and frag b128 reads
// both land 2-way-per-bank (free). ACT: 0 none, 1 relu, 2 elu.
template <int ACT, int BF16OUT>
__global__ __launch_bounds__(256) void mgemm_k(
    const __hip_bfloat16* __restrict__ A, const __hip_bfloat16* __restrict__ Bt,
    const float* __restrict__ bias, float* __restrict__ Cf,
    __hip_bfloat16* __restrict__ Cb, int ldc, int M, int N, int K) {
  __shared__ short As[128 * 40];
  __shared__ short Bs[128 * 40];
  int tid = threadIdx.x;
  int row0 = blockIdx.y * 128, col0 = blockIdx.x * 128;
  int w = tid >> 6, lane = tid & 63;
  int wr = w >> 1, wc = w & 1;
  int quad = lane >> 4, l16 = lane & 15;
  floatx4 zero = {0.f, 0.f, 0.f, 0.f};
  floatx4 acc[4][4];
#pragma unroll
  for (int i = 0; i < 4; i++)
#pragma unroll
    for (int j = 0; j < 4; j++) acc[i][j] = zero;

  int srow = tid >> 2;  // 0..63
  int sq = tid & 3;     // 16B chunk within 64B row
  const __hip_bfloat16* Ap1 = A + (size_t)(row0 + srow) * K + sq * 8;
  const __hip_bfloat16* Ap2 = A + (size_t)(row0 + 64 + srow) * K + sq * 8;
  const __hip_bfloat16* Bp1 = Bt + (size_t)(col0 + srow) * K + sq * 8;
  const __hip_bfloat16* Bp2 = Bt + (size_t)(col0 + 64 + srow) * K + sq * 8;
  bool aok1 = (row0 + srow) < M, aok2 = (row0 + 64 + srow) < M;

  for (int k0 = 0; k0 < K; k0 += 32) {
    uint4 a1 = make_uint4(0, 0, 0, 0), a2 = make_uint4(0, 0, 0, 0);
    if (aok1) a1 = *(const uint4*)(Ap1 + k0);
    if (aok2) a2 = *(const uint4*)(Ap2 + k0);
    uint4 b1 = *(const uint4*)(Bp1 + k0);
    uint4 b2 = *(const uint4*)(Bp2 + k0);
    __syncthreads();
    *(uint4*)&As[srow * 40 + sq * 8] = a1;
    *(uint4*)&As[(64 + srow) * 40 + sq * 8] = a2;
    *(uint4*)&Bs[srow * 40 + sq * 8] = b1;
    *(uint4*)&Bs[(64 + srow) * 40 + sq * 8] = b2;
    __syncthreads();
    short8 fa[4], fb[4];
#pragma unroll
    for (int i = 0; i < 4; i++) {
      fa[i] = *(const short8*)&As[(wr * 64 + i * 16 + l16) * 40 + quad * 8];
      fb[i] = *(const short8*)&Bs[(wc * 64 + i * 16 + l16) * 40 + quad * 8];
    }
#pragma unroll
    for (int mi = 0; mi < 4; mi++)
#pragma unroll
      for (int ni = 0; ni < 4; ni++)
        acc[mi][ni] = __builtin_amdgcn_mfma_f32_16x16x32_bf16(fa[mi], fb[ni], acc[mi][ni], 0, 0, 0);
  }

#pragma unroll
  for (int mi = 0; mi < 4; mi++) {
    int rbase = row0 + wr * 64 + mi * 16 + quad * 4;
#pragma unroll
    for (int ni = 0; ni < 4; ni++) {
      int c = col0 + wc * 64 + ni * 16 + l16;
      float bv = bias ? bias[c] : 0.f;
#pragma unroll
      for (int reg = 0; reg < 4; reg++) {
        int rr = rbase + reg;
        if (rr >= M) continue;
        float v = acc[mi][ni][reg] + bv;
        if (ACT == 1) v = fmaxf(v, 0.f);
        if (ACT == 2) v = elu_f(v);
        if (BF16OUT) Cb[(size_t)rr * ldc + c] = __float2bfloat16(v);
        else Cf[(size_t)rr * ldc + c] = v;
      }
    }
  }
}

// ---------------- GAT alpha ----------------
__global__ void alpha_small_k(const __hip_bfloat16* __restrict__ hW, const float* __restrict__ a_s,
                              const float* __restrict__ a_d, float* __restrict__ as_,
                              float* __restrict__ ad_, int M) {
  int idx = blockIdx.x * blockDim.x + threadIdx.x;
  if (idx >= M * HEADS) return;
  int h = idx & 7;
  const __hip_bfloat16* row = hW + (size_t)(idx >> 3) * HID + h * 32;
  const float* ws = a_s + h * 32;
  const float* wd = a_d + h * 32;
  float s = 0.f, d = 0.f;
#pragma unroll
  for (int c = 0; c < 32; c++) {
    float v = __bfloat162float(row[c]);
    s += v * ws[c];
    d += v * wd[c];
  }
  as_[idx] = s;
  ad_[idx] = d;
}

__global__ void alpha_big_k(const __hip_bfloat16* __restrict__ hW, const float* __restrict__ a_s,
                            const float* __restrict__ a_d, float* __restrict__ as_,
                            float* __restrict__ ad_, int M) {
  int idx = blockIdx.x * blockDim.x + threadIdx.x;
  if (idx >= M * HEADS) return;
  int h = idx & 7;
  const __hip_bfloat16* row = hW + (size_t)(idx >> 3) * 2048 + h * 256;
  const float* ws = a_s + h * 256;
  const float* wd = a_d + h * 256;
  float s = 0.f, d = 0.f;
  for (int c = 0; c < 256; c++) {
    float v = __bfloat162float(row[c]);
    s += v * ws[c];
    d += v * wd[c];
  }
  as_[idx] = s;
  ad_[idx] = d;
}

// ---------------- GAT aggregate (C=32): softmax + gather + bias + elu -> bf16 ----
__global__ __launch_bounds__(64) void agg_small_k(
    const int* __restrict__ rp, const int* __restrict__ col,
    const __hip_bfloat16* __restrict__ hW, const float* __restrict__ as_,
    const float* __restrict__ ad_, const float* __restrict__ bias,
    __hip_bfloat16* __restrict__ out) {
  int dst = blockIdx.x;
  int t = threadIdx.x;
  int h = t >> 3;
  int c = t << 2;
  int beg = rp[dst], end = rp[dst + 1];
  float adv = ad_[dst * 8 + h];
  float m = -3.4e38f;
  for (int i = beg; i < end; i++) {
    int s = col[i];
    float e = as_[s * 8 + h] + adv;
    e = e > 0.f ? e : 0.2f * e;
    m = fmaxf(m, e);
  }
  float den = 0.f;
  float a0 = 0.f, a1 = 0.f, a2 = 0.f, a3 = 0.f;
  for (int i = beg; i < end; i++) {
    int s = col[i];
    float e = as_[s * 8 + h] + adv;
    e = e > 0.f ? e : 0.2f * e;
    float ex = __expf(e - m);
    den += ex;
    union { uint2 u; unsigned short us[4]; } uu;
    uu.u = *(const uint2*)(hW + (size_t)s * HID + c);
    a0 += ex * bf2f(uu.us[0]);
    a1 += ex * bf2f(uu.us[1]);
    a2 += ex * bf2f(uu.us[2]);
    a3 += ex * bf2f(uu.us[3]);
  }
  float inv = 1.f / (den + 1e-16f);
  out[(size_t)dst * HID + c + 0] = __float2bfloat16(elu_f(a0 * inv + bias[c + 0]));
  out[(size_t)dst * HID + c + 1] = __float2bfloat16(elu_f(a1 * inv + bias[c + 1]));
  out[(size_t)dst * HID + c + 2] = __float2bfloat16(elu_f(a2 * inv + bias[c + 2]));
  out[(size_t)dst * HID + c + 3] = __float2bfloat16(elu_f(a3 * inv + bias[c + 3]));
}

// ---------------- GAT layer-3 aggregate (C=256) + bias + elu + head-mean -> comb[:,0:256] bf16
__global__ __launch_bounds__(256) void agg_big_k(
    const int* __restrict__ rp, const int* __restrict__ col,
    const __hip_bfloat16* __restrict__ hW, const float* __restrict__ as_,
    const float* __restrict__ ad_, const float* __restrict__ bias,
    __hip_bfloat16* __restrict__ comb) {
  int dst = blockIdx.x;
  int t = threadIdx.x;
  int beg = rp[dst], end = rp[dst + 1];
  float adv[8], m[8], den[8], acc[8];
#pragma unroll
  for (int h = 0; h < 8; h++) {
    adv[h] = ad_[dst * 8 + h];
    m[h] = -3.4e38f;
    den[h] = 0.f;
    acc[h] = 0.f;
  }
  for (int i = beg; i < end; i++) {
    int s = col[i];
#pragma unroll
    for (int h = 0; h < 8; h++) {
      float e = as_[s * 8 + h] + adv[h];
      e = e > 0.f ? e : 0.2f * e;
      m[h] = fmaxf(m[h], e);
    }
  }
  for (int i = beg; i < end; i++) {
    int s = col[i];
    const __hip_bfloat16* hrow = hW + (size_t)s * 2048 + t;
#pragma unroll
    for (int h = 0; h < 8; h++) {
      float e = as_[s * 8 + h] + adv[h];
      e = e > 0.f ? e : 0.2f * e;
      float ex = __expf(e - m[h]);
      den[h] += ex;
      acc[h] += ex * __bfloat162float(hrow[h * 256]);
    }
  }
  float g = 0.f;
#pragma unroll
  for (int h = 0; h < 8; h++) {
    float v = acc[h] / (den[h] + 1e-16f) + bias[h * 256 + t];
    g += elu_f(v);
  }
  comb[(size_t)dst * 512 + t] = __float2bfloat16(g * 0.125f);
}

// ---------------- final: logits = hidden @ w_c2 + b_c2 ----------------
__global__ __launch_bounds__(64) void final_k(const float* __restrict__ hidden,
                                              const float* __restrict__ w,
                                              const float* __restrict__ b,
                                              float* __restrict__ out) {
  int n = blockIdx.x;
  int l = threadIdx.x;
  const float* hr = hidden + (size_t)n * HID;
  float a0 = 0.f, a1 = 0.f;
  for (int k = l; k < HID; k += 64) {
    float hv = hr[k];
    a0 += hv * w[k * 2 + 0];
    a1 += hv * w[k * 2 + 1];
  }
  for (int off = 32; off > 0; off >>= 1) {
    a0 += __shfl_down(a0, off);
    a1 += __shfl_down(a1, off);
  }
  if (l == 0) {
    out[n * 2 + 0] = a0 + b[0];
    out[n * 2 + 1] = a1 + b[1];
  }
}

extern "C" void kernel_launch(void* const* d_in, const int* in_sizes, int n_in,
                              void* d_out, int out_size, void* d_ws, size_t ws_size,
                              hipStream_t stream) {
  const float* x      = (const float*)d_in[0];
  const int*   ei     = (const int*)d_in[1];
  const float* w_in   = (const float*)d_in[2];
  const float* b_in   = (const float*)d_in[3];
  const float* w_t1   = (const float*)d_in[4];
  const float* b_t1   = (const float*)d_in[5];
  const float* w_t2   = (const float*)d_in[6];
  const float* b_t2   = (const float*)d_in[7];
  const float* w_g1   = (const float*)d_in[8];
  const float* a_src1 = (const float*)d_in[9];
  const float* a_dst1 = (const float*)d_in[10];
  const float* b_g1   = (const float*)d_in[11];
  const float* w_g2   = (const float*)d_in[12];
  const float* a_src2 = (const float*)d_in[13];
  const float* a_dst2 = (const float*)d_in[14];
  const float* b_g2   = (const float*)d_in[15];
  const float* w_g3   = (const float*)d_in[16];
  const float* a_src3 = (const float*)d_in[17];
  const float* a_dst3 = (const float*)d_in[18];
  const float* b_g3   = (const float*)d_in[19];
  const float* w_c1   = (const float*)d_in[20];
  const float* b_c1   = (const float*)d_in[21];
  const float* w_c2   = (const float*)d_in[22];
  const float* b_c2   = (const float*)d_in[23];
  const int M = in_sizes[0] / FIN;  // 20000
  const int E = in_sizes[1] / 2;    // 120000
  (void)n_in; (void)out_size; (void)ws_size;

  char* wsb = (char*)d_ws;
  size_t off = 0;
  auto alloc = [&](size_t bytes) {
    void* p = wsb + off;
    off = (off + bytes + 255) & ~(size_t)255;
    return p;
  };
  typedef __hip_bfloat16 bf;
  bf* xb    = (bf*)alloc((size_t)M * 256 * 2);
  bf* wtin  = (bf*)alloc(256 * 256 * 2);
  bf* wtt1  = (bf*)alloc(256 * 256 * 2);
  bf* wtt2  = (bf*)alloc(256 * 256 * 2);
  bf* wtg1  = (bf*)alloc(256 * 256 * 2);
  bf* wtg2  = (bf*)alloc(256 * 256 * 2);
  bf* wtg3  = (bf*)alloc(2048 * 256 * 2);
  bf* wtc1  = (bf*)alloc(256 * 512 * 2);
  bf* actA  = (bf*)alloc((size_t)M * HID * 2);       // h, later g2
  bf* actB  = (bf*)alloc((size_t)M * HID * 2);       // th, later g1
  bf* comb  = (bf*)alloc((size_t)M * 2 * HID * 2);   // [g | t]
  void* hWreg = alloc((size_t)M * 2048 * 2);         // bf16 [M,2048]; reused f32 [M,256]
  bf* hWb   = (bf*)hWreg;
  float* hidden = (float*)hWreg;
  float* as_ = (float*)alloc((size_t)M * 8 * 4);
  float* ad_ = (float*)alloc((size_t)M * 8 * 4);
  int* deg   = (int*)alloc((size_t)M * 4);
  int* fillc = (int*)alloc((size_t)M * 4);
  int* rp    = (int*)alloc((size_t)(M + 1) * 4);
  int* colA  = (int*)alloc((size_t)(E + M) * 4);

  // ---- conversions ----
  xcvt_k<<<(M * 256 + 255) / 256, 256, 0, stream>>>(x, xb, M);
  dim3 tb(32, 8);
  tcvt_k<<<dim3(256 / 32, 256 / 32), tb, 0, stream>>>(w_in, wtin, FIN, 256, 256);
  tcvt_k<<<dim3(256 / 32, 256 / 32), tb, 0, stream>>>(w_t1, wtt1, 256, 256, 256);
  tcvt_k<<<dim3(256 / 32, 256 / 32), tb, 0, stream>>>(w_t2, wtt2, 256, 256, 256);
  tcvt_k<<<dim3(256 / 32, 256 / 32), tb, 0, stream>>>(w_g1, wtg1, 256, 256, 256);
  tcvt_k<<<dim3(256 / 32, 256 / 32), tb, 0, stream>>>(w_g2, wtg2, 256, 256, 256);
  tcvt_k<<<dim3(2048 / 32, 256 / 32), tb, 0, stream>>>(w_g3, wtg3, 256, 256, 2048);
  tcvt_k<<<dim3(256 / 32, 512 / 32), tb, 0, stream>>>(w_c1, wtc1, 512, 512, 256);

  // ---- CSR build ----
  init_deg_k<<<(M + 255) / 256, 256, 0, stream>>>(deg, fillc, M);
  count_k<<<(E + 255) / 256, 256, 0, stream>>>(ei, deg, E);
  scan_k<<<1, 1024, 0, stream>>>(deg, rp, M);
  fill_k<<<(E + M + 255) / 256, 256, 0, stream>>>(ei, rp, fillc, colA, E, M);

  auto gemm = [&](const bf* A, const bf* Bt, const float* bias, float* Cf, bf* Cb,
                  int ldc, int m, int n, int k, int act) {
    dim3 g(n / 128, (m + 127) / 128);
    if (Cb) {
      if (act == 0)      mgemm_k<0, 1><<<g, 256, 0, stream>>>(A, Bt, bias, nullptr, Cb, ldc, m, n, k);
      else if (act == 1) mgemm_k<1, 1><<<g, 256, 0, stream>>>(A, Bt, bias, nullptr, Cb, ldc, m, n, k);
      else               mgemm_k<2, 1><<<g, 256, 0, stream>>>(A, Bt, bias, nullptr, Cb, ldc, m, n, k);
    } else {
      if (act == 0)      mgemm_k<0, 0><<<g, 256, 0, stream>>>(A, Bt, bias, Cf, nullptr, ldc, m, n, k);
      else if (act == 1) mgemm_k<1, 0><<<g, 256, 0, stream>>>(A, Bt, bias, Cf, nullptr, ldc, m, n, k);
      else               mgemm_k<2, 0><<<g, 256, 0, stream>>>(A, Bt, bias, Cf, nullptr, ldc, m, n, k);
    }
  };

  // h = elu(x @ w_in + b_in)          -> actA bf16
  gemm(xb, wtin, b_in, nullptr, actA, HID, M, HID, 256, 2);
  // th = relu(h @ w_t1 + b_t1)        -> actB
  gemm(actA, wtt1, b_t1, nullptr, actB, HID, M, HID, 256, 1);
  // t = th @ w_t2 + b_t2              -> comb[:,256:512]
  gemm(actB, wtt2, b_t2, nullptr, comb + HID, 2 * HID, M, HID, 256, 0);

  // ---- GAT 1 ----
  gemm(actA, wtg1, nullptr, nullptr, hWb, HID, M, HID, 256, 0);
  alpha_small_k<<<(M * 8 + 63) / 64, 64, 0, stream>>>(hWb, a_src1, a_dst1, as_, ad_, M);
  agg_small_k<<<M, 64, 0, stream>>>(rp, colA, hWb, as_, ad_, b_g1, actB);  // g1

  // ---- GAT 2 ----
  gemm(actB, wtg2, nullptr, nullptr, hWb, HID, M, HID, 256, 0);
  alpha_small_k<<<(M * 8 + 63) / 64, 64, 0, stream>>>(hWb, a_src2, a_dst2, as_, ad_, M);
  agg_small_k<<<M, 64, 0, stream>>>(rp, colA, hWb, as_, ad_, b_g2, actA);  // g2

  // ---- GAT 3 (wide) ----
  gemm(actA, wtg3, nullptr, nullptr, hWb, 2048, M, 2048, 256, 0);
  alpha_big_k<<<(M * 8 + 63) / 64, 64, 0, stream>>>(hWb, a_src3, a_dst3, as_, ad_, M);
  agg_big_k<<<M, 256, 0, stream>>>(rp, colA, hWb, as_, ad_, b_g3, comb);

  // ---- classifier ----
  gemm(comb, wtc1, b_c1, hidden, nullptr, HID, M, HID, 512, 1);  // hidden f32 (reuses hW region)
  final_k<<<M, 64, 0, stream>>>(hidden, w_c2, b_c2, (float*)d_out);
}

// Round 3
// 562.980 us; speedup vs baseline: 2.0388x; 1.0676x over previous
//
#include <hip/hip_runtime.h>
#include <hip/hip_bf16.h>
#include <math.h>

// CHRONOS inference. Round 3: GAT3 reordered (aggregate g2 first, project
// after) -> gather reads 512B rows from a 10MB L3-resident table instead of
// 4KB rows from 82MB. Shared edge-softmax kernel precomputes ex/invden once
// per layer (kills redundant exp in agg kernels). Fused head-chunked GEMM
// (K=2048, elu+bias fold per 256, mean over 8 heads) writes comb directly.

#define HID 256
#define HEADS 8
#define FIN 235

typedef __attribute__((ext_vector_type(8))) short short8;
typedef __attribute__((ext_vector_type(4))) float floatx4;

__device__ __forceinline__ float elu_f(float x) { return x > 0.f ? x : expm1f(x); }
__device__ __forceinline__ float bf2f(unsigned short u) {
  return __uint_as_float(((unsigned int)u) << 16);
}

// ---------------- conversions ----------------
__global__ void xcvt_k(const float* __restrict__ x, __hip_bfloat16* __restrict__ xb, int M) {
  int id = blockIdx.x * blockDim.x + threadIdx.x;
  if (id >= M * 256) return;
  int m = id >> 8, k = id & 255;
  xb[id] = (k < FIN) ? __float2bfloat16(x[(size_t)m * FIN + k]) : __float2bfloat16(0.f);
}

// wt[n*Kpad + k] = w[k*Nstride + n] (bf16), zero-pad k in [K, Kpad)
__global__ void tcvt_k(const float* __restrict__ w, __hip_bfloat16* __restrict__ wt,
                       int K, int Kpad, int Nstride) {
  __shared__ float t[32][33];
  int nb = blockIdx.x * 32, kb = blockIdx.y * 32;
  int tx = threadIdx.x, ty = threadIdx.y;
#pragma unroll
  for (int j = 0; j < 32; j += 8) {
    int k = kb + ty + j;
    t[ty + j][tx] = (k < K) ? w[(size_t)k * Nstride + nb + tx] : 0.f;
  }
  __syncthreads();
#pragma unroll
  for (int j = 0; j < 32; j += 8) {
    int n = nb + ty + j;
    int k = kb + tx;
    wt[(size_t)n * Kpad + k] = __float2bfloat16(t[tx][ty + j]);
  }
}

// ---------------- CSR build ----------------
__global__ void init_deg_k(int* __restrict__ deg, int* __restrict__ fillc, int n) {
  int i = blockIdx.x * blockDim.x + threadIdx.x;
  if (i < n) { deg[i] = 1; fillc[i] = 0; }  // deg=1 accounts for self-loop
}

__global__ void count_k(const int* __restrict__ ei, int* __restrict__ deg, int E) {
  int i = blockIdx.x * blockDim.x + threadIdx.x;
  if (i < E) atomicAdd(&deg[ei[E + i]], 1);
}

__global__ void scan_k(const int* __restrict__ deg, int* __restrict__ rp, int n) {
  __shared__ int wsum[16];
  __shared__ int s_carry;
  int tid = threadIdx.x, lane = tid & 63, wid = tid >> 6;
  if (tid == 0) { s_carry = 0; rp[0] = 0; }
  __syncthreads();
  for (int base = 0; base < n; base += 1024) {
    int i = base + tid;
    int x = (i < n) ? deg[i] : 0;
#pragma unroll
    for (int off = 1; off < 64; off <<= 1) {
      int y = __shfl_up(x, off);
      if (lane >= off) x += y;
    }
    if (lane == 63) wsum[wid] = x;
    __syncthreads();
    if (wid == 0 && lane < 16) {
      int s = wsum[lane];
#pragma unroll
      for (int off = 1; off < 16; off <<= 1) {
        int y = __shfl_up(s, off);
        if (lane >= off) s += y;
      }
      wsum[lane] = s;
    }
    __syncthreads();
    int offset = s_carry + (wid > 0 ? wsum[wid - 1] : 0);
    if (i < n) rp[i + 1] = offset + x;
    __syncthreads();
    if (tid == 1023) s_carry += wsum[15];
    __syncthreads();
  }
}

__global__ void fill_k(const int* __restrict__ ei, const int* __restrict__ rp,
                       int* __restrict__ fillc, int* __restrict__ colA, int E, int n) {
  int i = blockIdx.x * blockDim.x + threadIdx.x;
  if (i < E) {
    int d = ei[E + i];
    int pos = rp[d] + atomicAdd(&fillc[d], 1);
    colA[pos] = ei[i];
  } else if (i < E + n) {
    int v = i - E;
    int pos = rp[v] + atomicAdd(&fillc[v], 1);
    colA[pos] = v;
  }
}

// ---------------- bf16 MFMA GEMM (generic) ----------------
template <int ACT, int BF16OUT>
__global__ __launch_bounds__(256) void mgemm_k(
    const __hip_bfloat16* __restrict__ A, const __hip_bfloat16* __restrict__ Bt,
    const float* __restrict__ bias, float* __restrict__ Cf,
    __hip_bfloat16* __restrict__ Cb, int ldc, int M, int N, int K) {
  __shared__ short As[128 * 40];
  __shared__ short Bs[128 * 40];
  int tid = threadIdx.x;
  int row0 = blockIdx.y * 128, col0 = blockIdx.x * 128;
  int w = tid >> 6, lane = tid & 63;
  int wr = w >> 1, wc = w & 1;
  int quad = lane >> 4, l16 = lane & 15;
  floatx4 zero = {0.f, 0.f, 0.f, 0.f};
  floatx4 acc[4][4];
#pragma unroll
  for (int i = 0; i < 4; i++)
#pragma unroll
    for (int j = 0; j < 4; j++) acc[i][j] = zero;

  int srow = tid >> 2;
  int sq = tid & 3;
  const __hip_bfloat16* Ap1 = A + (size_t)(row0 + srow) * K + sq * 8;
  const __hip_bfloat16* Ap2 = A + (size_t)(row0 + 64 + srow) * K + sq * 8;
  const __hip_bfloat16* Bp1 = Bt + (size_t)(col0 + srow) * K + sq * 8;
  const __hip_bfloat16* Bp2 = Bt + (size_t)(col0 + 64 + srow) * K + sq * 8;
  bool aok1 = (row0 + srow) < M, aok2 = (row0 + 64 + srow) < M;

  for (int k0 = 0; k0 < K; k0 += 32) {
    uint4 a1 = make_uint4(0, 0, 0, 0), a2 = make_uint4(0, 0, 0, 0);
    if (aok1) a1 = *(const uint4*)(Ap1 + k0);
    if (aok2) a2 = *(const uint4*)(Ap2 + k0);
    uint4 b1 = *(const uint4*)(Bp1 + k0);
    uint4 b2 = *(const uint4*)(Bp2 + k0);
    __syncthreads();
    *(uint4*)&As[srow * 40 + sq * 8] = a1;
    *(uint4*)&As[(64 + srow) * 40 + sq * 8] = a2;
    *(uint4*)&Bs[srow * 40 + sq * 8] = b1;
    *(uint4*)&Bs[(64 + srow) * 40 + sq * 8] = b2;
    __syncthreads();
    short8 fa[4], fb[4];
#pragma unroll
    for (int i = 0; i < 4; i++) {
      fa[i] = *(const short8*)&As[(wr * 64 + i * 16 + l16) * 40 + quad * 8];
      fb[i] = *(const short8*)&Bs[(wc * 64 + i * 16 + l16) * 40 + quad * 8];
    }
#pragma unroll
    for (int mi = 0; mi < 4; mi++)
#pragma unroll
      for (int ni = 0; ni < 4; ni++)
        acc[mi][ni] = __builtin_amdgcn_mfma_f32_16x16x32_bf16(fa[mi], fb[ni], acc[mi][ni], 0, 0, 0);
  }

#pragma unroll
  for (int mi = 0; mi < 4; mi++) {
    int rbase = row0 + wr * 64 + mi * 16 + quad * 4;
#pragma unroll
    for (int ni = 0; ni < 4; ni++) {
      int c = col0 + wc * 64 + ni * 16 + l16;
      float bv = bias ? bias[c] : 0.f;
#pragma unroll
      for (int reg = 0; reg < 4; reg++) {
        int rr = rbase + reg;
        if (rr >= M) continue;
        float v = acc[mi][ni][reg] + bv;
        if (ACT == 1) v = fmaxf(v, 0.f);
        if (ACT == 2) v = elu_f(v);
        if (BF16OUT) Cb[(size_t)rr * ldc + c] = __float2bfloat16(v);
        else Cf[(size_t)rr * ldc + c] = v;
      }
    }
  }
}

// ---------------- fused GAT3 GEMM: comb[:,0:256] = mean_h elu(agg_h @ W_h + b_h) ----
// A [M,2048] bf16 (K index = h*256+c), Bt [256,2048] bf16 (Bt[oc, h*256+c] =
// w_g3[c, h*256+oc]). N=256 fixed (grid.x=2). Fold elu+bias per 256-chunk.
__global__ __launch_bounds__(256) void mgemm3_k(
    const __hip_bfloat16* __restrict__ A, const __hip_bfloat16* __restrict__ Bt,
    const float* __restrict__ bias, __hip_bfloat16* __restrict__ comb, int M) {
  __shared__ short As[128 * 40];
  __shared__ short Bs[128 * 40];
  int tid = threadIdx.x;
  int row0 = blockIdx.y * 128, col0 = blockIdx.x * 128;
  int w = tid >> 6, lane = tid & 63;
  int wr = w >> 1, wc = w & 1;
  int quad = lane >> 4, l16 = lane & 15;
  floatx4 zero = {0.f, 0.f, 0.f, 0.f};
  floatx4 acc[4][4], sum[4][4];
#pragma unroll
  for (int i = 0; i < 4; i++)
#pragma unroll
    for (int j = 0; j < 4; j++) { acc[i][j] = zero; sum[i][j] = zero; }

  int srow = tid >> 2;
  int sq = tid & 3;
  const __hip_bfloat16* Ap1 = A + (size_t)(row0 + srow) * 2048 + sq * 8;
  const __hip_bfloat16* Ap2 = A + (size_t)(row0 + 64 + srow) * 2048 + sq * 8;
  const __hip_bfloat16* Bp1 = Bt + (size_t)(col0 + srow) * 2048 + sq * 8;
  const __hip_bfloat16* Bp2 = Bt + (size_t)(col0 + 64 + srow) * 2048 + sq * 8;
  bool aok1 = (row0 + srow) < M, aok2 = (row0 + 64 + srow) < M;

  for (int h = 0; h < 8; h++) {
    for (int kc = 0; kc < 256; kc += 32) {
      int k0 = h * 256 + kc;
      uint4 a1 = make_uint4(0, 0, 0, 0), a2 = make_uint4(0, 0, 0, 0);
      if (aok1) a1 = *(const uint4*)(Ap1 + k0);
      if (aok2) a2 = *(const uint4*)(Ap2 + k0);
      uint4 b1 = *(const uint4*)(Bp1 + k0);
      uint4 b2 = *(const uint4*)(Bp2 + k0);
      __syncthreads();
      *(uint4*)&As[srow * 40 + sq * 8] = a1;
      *(uint4*)&As[(64 + srow) * 40 + sq * 8] = a2;
      *(uint4*)&Bs[srow * 40 + sq * 8] = b1;
      *(uint4*)&Bs[(64 + srow) * 40 + sq * 8] = b2;
      __syncthreads();
      short8 fa[4], fb[4];
#pragma unroll
      for (int i = 0; i < 4; i++) {
        fa[i] = *(const short8*)&As[(wr * 64 + i * 16 + l16) * 40 + quad * 8];
        fb[i] = *(const short8*)&Bs[(wc * 64 + i * 16 + l16) * 40 + quad * 8];
      }
#pragma unroll
      for (int mi = 0; mi < 4; mi++)
#pragma unroll
        for (int ni = 0; ni < 4; ni++)
          acc[mi][ni] = __builtin_amdgcn_mfma_f32_16x16x32_bf16(fa[mi], fb[ni], acc[mi][ni], 0, 0, 0);
    }
    // fold: elu(acc + bias_h) into running head-sum, reset acc
#pragma unroll
    for (int mi = 0; mi < 4; mi++)
#pragma unroll
      for (int ni = 0; ni < 4; ni++) {
        int c = col0 + wc * 64 + ni * 16 + l16;
        float bv = bias[h * 256 + c];
#pragma unroll
        for (int reg = 0; reg < 4; reg++) {
          sum[mi][ni][reg] += elu_f(acc[mi][ni][reg] + bv);
          acc[mi][ni][reg] = 0.f;
        }
      }
  }

#pragma unroll
  for (int mi = 0; mi < 4; mi++) {
    int rbase = row0 + wr * 64 + mi * 16 + quad * 4;
#pragma unroll
    for (int ni = 0; ni < 4; ni++) {
      int c = col0 + wc * 64 + ni * 16 + l16;
#pragma unroll
      for (int reg = 0; reg < 4; reg++) {
        int rr = rbase + reg;
        if (rr >= M) continue;
        comb[(size_t)rr * 512 + c] = __float2bfloat16(sum[mi][ni][reg] * 0.125f);
      }
    }
  }
}

// ---------------- attention-vector projection for GAT3 ----------------
// apj[k*16 + h*2 + sd] = sum_c w_g3[k, h*256+c] * a_{src,dst}3[h,c]
__global__ void aproj_k(const float* __restrict__ w_g3, const float* __restrict__ a_s,
                        const float* __restrict__ a_d, float* __restrict__ apj) {
  int idx = blockIdx.x * blockDim.x + threadIdx.x;
  if (idx >= 256 * 16) return;
  int k = idx >> 4, o = idx & 15;
  int h = o >> 1;
  const float* av = (o & 1) ? (a_d + h * 256) : (a_s + h * 256);
  const float* wr = w_g3 + (size_t)k * 2048 + h * 256;
  float s = 0.f;
  for (int c = 0; c < 256; c++) s += wr[c] * av[c];
  apj[idx] = s;
}

// alpha logits for GAT3 from g2: block = 16 nodes x 16 outputs
__global__ __launch_bounds__(256) void alpha3_k(const __hip_bfloat16* __restrict__ g2,
                                                const float* __restrict__ apj,
                                                float* __restrict__ as_, float* __restrict__ ad_,
                                                int M) {
  int tid = threadIdx.x;
  int nl = tid >> 4, o = tid & 15;
  int n = blockIdx.x * 16 + nl;
  if (n >= M) return;
  const __hip_bfloat16* row = g2 + (size_t)n * 256;
  float s = 0.f;
  for (int c = 0; c < 256; c++) s += __bfloat162float(row[c]) * apj[c * 16 + o];
  if (o & 1) ad_[n * 8 + (o >> 1)] = s;
  else as_[n * 8 + (o >> 1)] = s;
}

// ---------------- GAT alpha logits (layers 1/2) ----------------
__global__ void alpha_small_k(const __hip_bfloat16* __restrict__ hW, const float* __restrict__ a_s,
                              const float* __restrict__ a_d, float* __restrict__ as_,
                              float* __restrict__ ad_, int M) {
  int idx = blockIdx.x * blockDim.x + threadIdx.x;
  if (idx >= M * HEADS) return;
  int h = idx & 7;
  const __hip_bfloat16* row = hW + (size_t)(idx >> 3) * HID + h * 32;
  const float* ws = a_s + h * 32;
  const float* wd = a_d + h * 32;
  float s = 0.f, d = 0.f;
#pragma unroll
  for (int c = 0; c < 32; c++) {
    float v = __bfloat162float(row[c]);
    s += v * ws[c];
    d += v * wd[c];
  }
  as_[idx] = s;
  ad_[idx] = d;
}

// ---------------- edge softmax: ex (unnormalized) + invden, one wave/dst ----
// lane = edge_slot*8 + head
__global__ __launch_bounds__(256) void esoft_k(const int* __restrict__ rp,
                                               const int* __restrict__ col,
                                               const float* __restrict__ as_,
                                               const float* __restrict__ ad_,
                                               float* __restrict__ ex,
                                               float* __restrict__ invden, int M) {
  int dst = blockIdx.x * 4 + (threadIdx.x >> 6);
  if (dst >= M) return;
  int lane = threadIdx.x & 63;
  int es = lane >> 3, h = lane & 7;
  int beg = rp[dst], end = rp[dst + 1];
  float adv = ad_[dst * 8 + h];
  float m = -3.4e38f;
  for (int i = beg + es; i < end; i += 8) {
    float e = as_[col[i] * 8 + h] + adv;
    e = e > 0.f ? e : 0.2f * e;
    m = fmaxf(m, e);
  }
  m = fmaxf(m, __shfl_xor(m, 8));
  m = fmaxf(m, __shfl_xor(m, 16));
  m = fmaxf(m, __shfl_xor(m, 32));
  float den = 0.f;
  for (int i = beg + es; i < end; i += 8) {
    float e = as_[col[i] * 8 + h] + adv;
    e = e > 0.f ? e : 0.2f * e;
    float v = __expf(e - m);
    ex[(size_t)i * 8 + h] = v;
    den += v;
  }
  den += __shfl_xor(den, 8);
  den += __shfl_xor(den, 16);
  den += __shfl_xor(den, 32);
  if (es == 0) invden[dst * 8 + h] = 1.f / (den + 1e-16f);
}

// ---------------- weighted aggregate, C=32/head (GAT1/2) ----------------
__global__ __launch_bounds__(64) void aggw_k(const int* __restrict__ rp,
                                             const int* __restrict__ col,
                                             const __hip_bfloat16* __restrict__ hW,
                                             const float* __restrict__ ex,
                                             const float* __restrict__ invden,
                                             const float* __restrict__ bias,
                                             __hip_bfloat16* __restrict__ out) {
  int dst = blockIdx.x;
  int t = threadIdx.x;
  int h = t >> 3, c = t << 2;
  int beg = rp[dst], end = rp[dst + 1];
  float a0 = 0.f, a1 = 0.f, a2 = 0.f, a3 = 0.f;
  for (int i = beg; i < end; i++) {
    int s = col[i];
    float wgt = ex[(size_t)i * 8 + h];
    union { uint2 u; unsigned short us[4]; } uu;
    uu.u = *(const uint2*)(hW + (size_t)s * HID + c);
    a0 += wgt * bf2f(uu.us[0]);
    a1 += wgt * bf2f(uu.us[1]);
    a2 += wgt * bf2f(uu.us[2]);
    a3 += wgt * bf2f(uu.us[3]);
  }
  float inv = invden[dst * 8 + h];
  out[(size_t)dst * HID + c + 0] = __float2bfloat16(elu_f(a0 * inv + bias[c + 0]));
  out[(size_t)dst * HID + c + 1] = __float2bfloat16(elu_f(a1 * inv + bias[c + 1]));
  out[(size_t)dst * HID + c + 2] = __float2bfloat16(elu_f(a2 * inv + bias[c + 2]));
  out[(size_t)dst * HID + c + 3] = __float2bfloat16(elu_f(a3 * inv + bias[c + 3]));
}

// ---------------- GAT3 aggregate: outA[dst, h*256+c] = invden_h * sum ex_h*g2[src,c] ----
__global__ __launch_bounds__(256) void agg3_k(const int* __restrict__ rp,
                                              const int* __restrict__ col,
                                              const __hip_bfloat16* __restrict__ g2,
                                              const float* __restrict__ ex,
                                              const float* __restrict__ invden,
                                              __hip_bfloat16* __restrict__ outA) {
  int dst = blockIdx.x;
  int t = threadIdx.x;
  int beg = rp[dst], end = rp[dst + 1];
  float acc[8] = {0.f, 0.f, 0.f, 0.f, 0.f, 0.f, 0.f, 0.f};
  for (int i = beg; i < end; i++) {
    int s = col[i];
    float4 w0 = *(const float4*)(ex + (size_t)i * 8);
    float4 w1 = *(const float4*)(ex + (size_t)i * 8 + 4);
    float v = __bfloat162float(g2[(size_t)s * 256 + t]);
    acc[0] += w0.x * v; acc[1] += w0.y * v; acc[2] += w0.z * v; acc[3] += w0.w * v;
    acc[4] += w1.x * v; acc[5] += w1.y * v; acc[6] += w1.z * v; acc[7] += w1.w * v;
  }
#pragma unroll
  for (int h = 0; h < 8; h++)
    outA[(size_t)dst * 2048 + h * 256 + t] =
        __float2bfloat16(acc[h] * invden[dst * 8 + h]);
}

// ---------------- final: logits = hidden @ w_c2 + b_c2 ----------------
__global__ __launch_bounds__(64) void final_k(const float* __restrict__ hidden,
                                              const float* __restrict__ w,
                                              const float* __restrict__ b,
                                              float* __restrict__ out) {
  int n = blockIdx.x;
  int l = threadIdx.x;
  const float* hr = hidden + (size_t)n * HID;
  float a0 = 0.f, a1 = 0.f;
  for (int k = l; k < HID; k += 64) {
    float hv = hr[k];
    a0 += hv * w[k * 2 + 0];
    a1 += hv * w[k * 2 + 1];
  }
  for (int off = 32; off > 0; off >>= 1) {
    a0 += __shfl_down(a0, off);
    a1 += __shfl_down(a1, off);
  }
  if (l == 0) {
    out[n * 2 + 0] = a0 + b[0];
    out[n * 2 + 1] = a1 + b[1];
  }
}

extern "C" void kernel_launch(void* const* d_in, const int* in_sizes, int n_in,
                              void* d_out, int out_size, void* d_ws, size_t ws_size,
                              hipStream_t stream) {
  const float* x      = (const float*)d_in[0];
  const int*   ei     = (const int*)d_in[1];
  const float* w_in   = (const float*)d_in[2];
  const float* b_in   = (const float*)d_in[3];
  const float* w_t1   = (const float*)d_in[4];
  const float* b_t1   = (const float*)d_in[5];
  const float* w_t2   = (const float*)d_in[6];
  const float* b_t2   = (const float*)d_in[7];
  const float* w_g1   = (const float*)d_in[8];
  const float* a_src1 = (const float*)d_in[9];
  const float* a_dst1 = (const float*)d_in[10];
  const float* b_g1   = (const float*)d_in[11];
  const float* w_g2   = (const float*)d_in[12];
  const float* a_src2 = (const float*)d_in[13];
  const float* a_dst2 = (const float*)d_in[14];
  const float* b_g2   = (const float*)d_in[15];
  const float* w_g3   = (const float*)d_in[16];
  const float* a_src3 = (const float*)d_in[17];
  const float* a_dst3 = (const float*)d_in[18];
  const float* b_g3   = (const float*)d_in[19];
  const float* w_c1   = (const float*)d_in[20];
  const float* b_c1   = (const float*)d_in[21];
  const float* w_c2   = (const float*)d_in[22];
  const float* b_c2   = (const float*)d_in[23];
  const int M = in_sizes[0] / FIN;  // 20000
  const int E = in_sizes[1] / 2;    // 120000
  (void)n_in; (void)out_size; (void)ws_size;

  char* wsb = (char*)d_ws;
  size_t off = 0;
  auto alloc = [&](size_t bytes) {
    void* p = wsb + off;
    off = (off + bytes + 255) & ~(size_t)255;
    return p;
  };
  typedef __hip_bfloat16 bf;
  bf* xb    = (bf*)alloc((size_t)M * 256 * 2);
  bf* wtin  = (bf*)alloc(256 * 256 * 2);
  bf* wtt1  = (bf*)alloc(256 * 256 * 2);
  bf* wtt2  = (bf*)alloc(256 * 256 * 2);
  bf* wtg1  = (bf*)alloc(256 * 256 * 2);
  bf* wtg2  = (bf*)alloc(256 * 256 * 2);
  bf* wtg3s = (bf*)alloc(256 * 2048 * 2);           // stacked per-head transposed W3
  bf* wtc1  = (bf*)alloc(256 * 512 * 2);
  bf* actA  = (bf*)alloc((size_t)M * HID * 2);      // h, later g2
  bf* actB  = (bf*)alloc((size_t)M * HID * 2);      // th, later g1
  bf* comb  = (bf*)alloc((size_t)M * 2 * HID * 2);  // [g | t]
  void* hWreg = alloc((size_t)M * 2048 * 2);        // hW1/hW2 bf16; agg3 out; hidden f32
  bf* hWb   = (bf*)hWreg;
  float* hidden = (float*)hWreg;
  float* as_ = (float*)alloc((size_t)M * 8 * 4);
  float* ad_ = (float*)alloc((size_t)M * 8 * 4);
  float* apj = (float*)alloc(256 * 16 * 4);
  float* exw = (float*)alloc((size_t)(E + M) * 8 * 4);
  float* ivd = (float*)alloc((size_t)M * 8 * 4);
  int* deg   = (int*)alloc((size_t)M * 4);
  int* fillc = (int*)alloc((size_t)M * 4);
  int* rp    = (int*)alloc((size_t)(M + 1) * 4);
  int* colA  = (int*)alloc((size_t)(E + M) * 4);

  // ---- conversions ----
  xcvt_k<<<(M * 256 + 255) / 256, 256, 0, stream>>>(x, xb, M);
  dim3 tb(32, 8);
  tcvt_k<<<dim3(8, 8), tb, 0, stream>>>(w_in, wtin, FIN, 256, 256);
  tcvt_k<<<dim3(8, 8), tb, 0, stream>>>(w_t1, wtt1, 256, 256, 256);
  tcvt_k<<<dim3(8, 8), tb, 0, stream>>>(w_t2, wtt2, 256, 256, 256);
  tcvt_k<<<dim3(8, 8), tb, 0, stream>>>(w_g1, wtg1, 256, 256, 256);
  tcvt_k<<<dim3(8, 8), tb, 0, stream>>>(w_g2, wtg2, 256, 256, 256);
  for (int h = 0; h < 8; h++)  // wtg3s[oc, h*256+c] = w_g3[c, h*256+oc]
    tcvt_k<<<dim3(8, 8), tb, 0, stream>>>(w_g3 + h * 256, wtg3s + h * 256, 256, 2048, 2048);
  tcvt_k<<<dim3(8, 16), tb, 0, stream>>>(w_c1, wtc1, 512, 512, 256);
  aproj_k<<<16, 256, 0, stream>>>(w_g3, a_src3, a_dst3, apj);

  // ---- CSR build ----
  init_deg_k<<<(M + 255) / 256, 256, 0, stream>>>(deg, fillc, M);
  count_k<<<(E + 255) / 256, 256, 0, stream>>>(ei, deg, E);
  scan_k<<<1, 1024, 0, stream>>>(deg, rp, M);
  fill_k<<<(E + M + 255) / 256, 256, 0, stream>>>(ei, rp, fillc, colA, E, M);

  auto gemm = [&](const bf* A, const bf* Bt, const float* bias, float* Cf, bf* Cb,
                  int ldc, int m, int n, int k, int act) {
    dim3 g(n / 128, (m + 127) / 128);
    if (Cb) {
      if (act == 0)      mgemm_k<0, 1><<<g, 256, 0, stream>>>(A, Bt, bias, nullptr, Cb, ldc, m, n, k);
      else if (act == 1) mgemm_k<1, 1><<<g, 256, 0, stream>>>(A, Bt, bias, nullptr, Cb, ldc, m, n, k);
      else               mgemm_k<2, 1><<<g, 256, 0, stream>>>(A, Bt, bias, nullptr, Cb, ldc, m, n, k);
    } else {
      if (act == 0)      mgemm_k<0, 0><<<g, 256, 0, stream>>>(A, Bt, bias, Cf, nullptr, ldc, m, n, k);
      else if (act == 1) mgemm_k<1, 0><<<g, 256, 0, stream>>>(A, Bt, bias, Cf, nullptr, ldc, m, n, k);
      else               mgemm_k<2, 0><<<g, 256, 0, stream>>>(A, Bt, bias, Cf, nullptr, ldc, m, n, k);
    }
  };
  int eg = (M + 3) / 4;

  // h = elu(x @ w_in + b_in) -> actA
  gemm(xb, wtin, b_in, nullptr, actA, HID, M, HID, 256, 2);
  // th = relu(h @ w_t1) -> actB ; t = th @ w_t2 -> comb[:,256:512]
  gemm(actA, wtt1, b_t1, nullptr, actB, HID, M, HID, 256, 1);
  gemm(actB, wtt2, b_t2, nullptr, comb + HID, 2 * HID, M, HID, 256, 0);

  // ---- GAT 1 ----
  gemm(actA, wtg1, nullptr, nullptr, hWb, HID, M, HID, 256, 0);
  alpha_small_k<<<(M * 8 + 63) / 64, 64, 0, stream>>>(hWb, a_src1, a_dst1, as_, ad_, M);
  esoft_k<<<eg, 256, 0, stream>>>(rp, colA, as_, ad_, exw, ivd, M);
  aggw_k<<<M, 64, 0, stream>>>(rp, colA, hWb, exw, ivd, b_g1, actB);  // g1

  // ---- GAT 2 ----
  gemm(actB, wtg2, nullptr, nullptr, hWb, HID, M, HID, 256, 0);
  alpha_small_k<<<(M * 8 + 63) / 64, 64, 0, stream>>>(hWb, a_src2, a_dst2, as_, ad_, M);
  esoft_k<<<eg, 256, 0, stream>>>(rp, colA, as_, ad_, exw, ivd, M);
  aggw_k<<<M, 64, 0, stream>>>(rp, colA, hWb, exw, ivd, b_g2, actA);  // g2

  // ---- GAT 3: logits from g2, aggregate g2, then fused projection ----
  alpha3_k<<<(M + 15) / 16, 256, 0, stream>>>(actA, apj, as_, ad_, M);
  esoft_k<<<eg, 256, 0, stream>>>(rp, colA, as_, ad_, exw, ivd, M);
  agg3_k<<<M, 256, 0, stream>>>(rp, colA, actA, exw, ivd, hWb);
  mgemm3_k<<<dim3(2, (M + 127) / 128), 256, 0, stream>>>(hWb, wtg3s, b_g3, comb, M);

  // ---- classifier ----
  gemm(comb, wtc1, b_c1, hidden, nullptr, HID, M, HID, 512, 1);
  final_k<<<M, 64, 0, stream>>>(hidden, w_c2, b_c2, (float*)d_out);
}

// Round 4
// 491.795 us; speedup vs baseline: 2.3340x; 1.1447x over previous
//
#include <hip/hip_runtime.h>
#include <hip/hip_bf16.h>
#include <math.h>

// CHRONOS inference. Round 4: TILE_M=64 MFMA GEMMs (2x the blocks -> 2.4-4.9
// blocks/CU, fixes the 1.2-block/CU latency wall seen in rocprof), register
// prefetch of next k-chunk, stacked dual GEMM for the two h-consumers,
// bfloat162-vectorized agg3.

#define HID 256
#define HEADS 8
#define FIN 235

typedef __attribute__((ext_vector_type(8))) short short8;
typedef __attribute__((ext_vector_type(4))) float floatx4;

__device__ __forceinline__ float elu_f(float x) { return x > 0.f ? x : expm1f(x); }
__device__ __forceinline__ float bf2f(unsigned short u) {
  return __uint_as_float(((unsigned int)u) << 16);
}
__device__ __forceinline__ unsigned short f2bfu(float f) {
  union { __hip_bfloat16 b; unsigned short u; } c;
  c.b = __float2bfloat16(f);
  return c.u;
}

// ---------------- conversions ----------------
__global__ void xcvt_k(const float* __restrict__ x, __hip_bfloat16* __restrict__ xb, int M) {
  int id = blockIdx.x * blockDim.x + threadIdx.x;
  if (id >= M * 256) return;
  int m = id >> 8, k = id & 255;
  xb[id] = (k < FIN) ? __float2bfloat16(x[(size_t)m * FIN + k]) : __float2bfloat16(0.f);
}

// wt[n*Kpad + k] = w[k*Nstride + n] (bf16), zero-pad k in [K, Kpad)
__global__ void tcvt_k(const float* __restrict__ w, __hip_bfloat16* __restrict__ wt,
                       int K, int Kpad, int Nstride) {
  __shared__ float t[32][33];
  int nb = blockIdx.x * 32, kb = blockIdx.y * 32;
  int tx = threadIdx.x, ty = threadIdx.y;
#pragma unroll
  for (int j = 0; j < 32; j += 8) {
    int k = kb + ty + j;
    t[ty + j][tx] = (k < K) ? w[(size_t)k * Nstride + nb + tx] : 0.f;
  }
  __syncthreads();
#pragma unroll
  for (int j = 0; j < 32; j += 8) {
    int n = nb + ty + j;
    int k = kb + tx;
    wt[(size_t)n * Kpad + k] = __float2bfloat16(t[tx][ty + j]);
  }
}

// ---------------- CSR build ----------------
__global__ void init_deg_k(int* __restrict__ deg, int* __restrict__ fillc, int n) {
  int i = blockIdx.x * blockDim.x + threadIdx.x;
  if (i < n) { deg[i] = 1; fillc[i] = 0; }
}

__global__ void count_k(const int* __restrict__ ei, int* __restrict__ deg, int E) {
  int i = blockIdx.x * blockDim.x + threadIdx.x;
  if (i < E) atomicAdd(&deg[ei[E + i]], 1);
}

__global__ void scan_k(const int* __restrict__ deg, int* __restrict__ rp, int n) {
  __shared__ int wsum[16];
  __shared__ int s_carry;
  int tid = threadIdx.x, lane = tid & 63, wid = tid >> 6;
  if (tid == 0) { s_carry = 0; rp[0] = 0; }
  __syncthreads();
  for (int base = 0; base < n; base += 1024) {
    int i = base + tid;
    int x = (i < n) ? deg[i] : 0;
#pragma unroll
    for (int off = 1; off < 64; off <<= 1) {
      int y = __shfl_up(x, off);
      if (lane >= off) x += y;
    }
    if (lane == 63) wsum[wid] = x;
    __syncthreads();
    if (wid == 0 && lane < 16) {
      int s = wsum[lane];
#pragma unroll
      for (int off = 1; off < 16; off <<= 1) {
        int y = __shfl_up(s, off);
        if (lane >= off) s += y;
      }
      wsum[lane] = s;
    }
    __syncthreads();
    int offset = s_carry + (wid > 0 ? wsum[wid - 1] : 0);
    if (i < n) rp[i + 1] = offset + x;
    __syncthreads();
    if (tid == 1023) s_carry += wsum[15];
    __syncthreads();
  }
}

__global__ void fill_k(const int* __restrict__ ei, const int* __restrict__ rp,
                       int* __restrict__ fillc, int* __restrict__ colA, int E, int n) {
  int i = blockIdx.x * blockDim.x + threadIdx.x;
  if (i < E) {
    int d = ei[E + i];
    int pos = rp[d] + atomicAdd(&fillc[d], 1);
    colA[pos] = ei[i];
  } else if (i < E + n) {
    int v = i - E;
    int pos = rp[v] + atomicAdd(&fillc[v], 1);
    colA[pos] = v;
  }
}

// ---------------- bf16 MFMA GEMM, TILE 64x128, BK=32, prefetch ----------------
// 4 waves: wave (wr,wc) computes rows [wr*32,+32) x cols [wc*64,+64): 2x4 frags.
template <int ACT, int BF16OUT>
__global__ __launch_bounds__(256) void mgemm_k(
    const __hip_bfloat16* __restrict__ A, const __hip_bfloat16* __restrict__ Bt,
    const float* __restrict__ bias, float* __restrict__ Cf,
    __hip_bfloat16* __restrict__ Cb, int ldc, int M, int N, int K) {
  __shared__ short As[64 * 40];
  __shared__ short Bs[128 * 40];
  int tid = threadIdx.x;
  int row0 = blockIdx.y * 64, col0 = blockIdx.x * 128;
  int w = tid >> 6, lane = tid & 63;
  int wr = w >> 1, wc = w & 1;
  int quad = lane >> 4, l16 = lane & 15;
  floatx4 zero = {0.f, 0.f, 0.f, 0.f};
  floatx4 acc[2][4];
#pragma unroll
  for (int i = 0; i < 2; i++)
#pragma unroll
    for (int j = 0; j < 4; j++) acc[i][j] = zero;

  int srow = tid >> 2;  // 0..63
  int sq = tid & 3;
  const __hip_bfloat16* Ap = A + (size_t)(row0 + srow) * K + sq * 8;
  const __hip_bfloat16* Bp1 = Bt + (size_t)(col0 + srow) * K + sq * 8;
  const __hip_bfloat16* Bp2 = Bt + (size_t)(col0 + 64 + srow) * K + sq * 8;
  bool aok = (row0 + srow) < M;

  uint4 a1 = make_uint4(0, 0, 0, 0);
  if (aok) a1 = *(const uint4*)(Ap);
  uint4 b1 = *(const uint4*)(Bp1);
  uint4 b2 = *(const uint4*)(Bp2);

  for (int k0 = 0; k0 < K; k0 += 32) {
    __syncthreads();
    *(uint4*)&As[srow * 40 + sq * 8] = a1;
    *(uint4*)&Bs[srow * 40 + sq * 8] = b1;
    *(uint4*)&Bs[(64 + srow) * 40 + sq * 8] = b2;
    int kn = k0 + 32;
    if (kn < K) {
      if (aok) a1 = *(const uint4*)(Ap + kn);
      b1 = *(const uint4*)(Bp1 + kn);
      b2 = *(const uint4*)(Bp2 + kn);
    }
    __syncthreads();
    short8 fa[2], fb[4];
#pragma unroll
    for (int i = 0; i < 2; i++)
      fa[i] = *(const short8*)&As[(wr * 32 + i * 16 + l16) * 40 + quad * 8];
#pragma unroll
    for (int i = 0; i < 4; i++)
      fb[i] = *(const short8*)&Bs[(wc * 64 + i * 16 + l16) * 40 + quad * 8];
#pragma unroll
    for (int mi = 0; mi < 2; mi++)
#pragma unroll
      for (int ni = 0; ni < 4; ni++)
        acc[mi][ni] = __builtin_amdgcn_mfma_f32_16x16x32_bf16(fa[mi], fb[ni], acc[mi][ni], 0, 0, 0);
  }

#pragma unroll
  for (int mi = 0; mi < 2; mi++) {
    int rbase = row0 + wr * 32 + mi * 16 + quad * 4;
#pragma unroll
    for (int ni = 0; ni < 4; ni++) {
      int c = col0 + wc * 64 + ni * 16 + l16;
      float bv = bias ? bias[c] : 0.f;
#pragma unroll
      for (int reg = 0; reg < 4; reg++) {
        int rr = rbase + reg;
        if (rr >= M) continue;
        float v = acc[mi][ni][reg] + bv;
        if (ACT == 1) v = fmaxf(v, 0.f);
        if (ACT == 2) v = elu_f(v);
        if (BF16OUT) Cb[(size_t)rr * ldc + c] = __float2bfloat16(v);
        else Cf[(size_t)rr * ldc + c] = v;
      }
    }
  }
}

// ---------------- dual GEMM: A@[w_t1 | w_g1], split epilogue ----------------
// cols [0,256): relu(+b_t1) -> O1 ; cols [256,512): raw -> O2. K=256.
__global__ __launch_bounds__(256) void mgemm_dual_k(
    const __hip_bfloat16* __restrict__ A, const __hip_bfloat16* __restrict__ Bt,
    const float* __restrict__ bias1, __hip_bfloat16* __restrict__ O1,
    __hip_bfloat16* __restrict__ O2, int M) {
  const int K = 256;
  __shared__ short As[64 * 40];
  __shared__ short Bs[128 * 40];
  int tid = threadIdx.x;
  int row0 = blockIdx.y * 64, col0 = blockIdx.x * 128;
  int w = tid >> 6, lane = tid & 63;
  int wr = w >> 1, wc = w & 1;
  int quad = lane >> 4, l16 = lane & 15;
  floatx4 zero = {0.f, 0.f, 0.f, 0.f};
  floatx4 acc[2][4];
#pragma unroll
  for (int i = 0; i < 2; i++)
#pragma unroll
    for (int j = 0; j < 4; j++) acc[i][j] = zero;

  int srow = tid >> 2, sq = tid & 3;
  const __hip_bfloat16* Ap = A + (size_t)(row0 + srow) * K + sq * 8;
  const __hip_bfloat16* Bp1 = Bt + (size_t)(col0 + srow) * K + sq * 8;
  const __hip_bfloat16* Bp2 = Bt + (size_t)(col0 + 64 + srow) * K + sq * 8;
  bool aok = (row0 + srow) < M;

  uint4 a1 = make_uint4(0, 0, 0, 0);
  if (aok) a1 = *(const uint4*)(Ap);
  uint4 b1 = *(const uint4*)(Bp1);
  uint4 b2 = *(const uint4*)(Bp2);

  for (int k0 = 0; k0 < K; k0 += 32) {
    __syncthreads();
    *(uint4*)&As[srow * 40 + sq * 8] = a1;
    *(uint4*)&Bs[srow * 40 + sq * 8] = b1;
    *(uint4*)&Bs[(64 + srow) * 40 + sq * 8] = b2;
    int kn = k0 + 32;
    if (kn < K) {
      if (aok) a1 = *(const uint4*)(Ap + kn);
      b1 = *(const uint4*)(Bp1 + kn);
      b2 = *(const uint4*)(Bp2 + kn);
    }
    __syncthreads();
    short8 fa[2], fb[4];
#pragma unroll
    for (int i = 0; i < 2; i++)
      fa[i] = *(const short8*)&As[(wr * 32 + i * 16 + l16) * 40 + quad * 8];
#pragma unroll
    for (int i = 0; i < 4; i++)
      fb[i] = *(const short8*)&Bs[(wc * 64 + i * 16 + l16) * 40 + quad * 8];
#pragma unroll
    for (int mi = 0; mi < 2; mi++)
#pragma unroll
      for (int ni = 0; ni < 4; ni++)
        acc[mi][ni] = __builtin_amdgcn_mfma_f32_16x16x32_bf16(fa[mi], fb[ni], acc[mi][ni], 0, 0, 0);
  }

#pragma unroll
  for (int mi = 0; mi < 2; mi++) {
    int rbase = row0 + wr * 32 + mi * 16 + quad * 4;
#pragma unroll
    for (int ni = 0; ni < 4; ni++) {
      int c = col0 + wc * 64 + ni * 16 + l16;
      bool first = c < 256;
      float bv = first ? bias1[c] : 0.f;
      int cc = first ? c : (c - 256);
#pragma unroll
      for (int reg = 0; reg < 4; reg++) {
        int rr = rbase + reg;
        if (rr >= M) continue;
        float v = acc[mi][ni][reg] + bv;
        if (first) v = fmaxf(v, 0.f);
        __hip_bfloat16* dst = first ? O1 : O2;
        dst[(size_t)rr * 256 + cc] = __float2bfloat16(v);
      }
    }
  }
}

// ---------------- fused GAT3 GEMM: comb[:,0:256] = mean_h elu(agg_h @ W_h + b_h) ----
// A [M,2048] bf16 (K = h*256+c, linear), Bt [256,2048]. TILE 64x128, fold
// elu+bias every 256 k. grid (2, ceil(M/64)).
__global__ __launch_bounds__(256) void mgemm3_k(
    const __hip_bfloat16* __restrict__ A, const __hip_bfloat16* __restrict__ Bt,
    const float* __restrict__ bias, __hip_bfloat16* __restrict__ comb, int M) {
  const int K = 2048;
  __shared__ short As[64 * 40];
  __shared__ short Bs[128 * 40];
  int tid = threadIdx.x;
  int row0 = blockIdx.y * 64, col0 = blockIdx.x * 128;
  int w = tid >> 6, lane = tid & 63;
  int wr = w >> 1, wc = w & 1;
  int quad = lane >> 4, l16 = lane & 15;
  floatx4 zero = {0.f, 0.f, 0.f, 0.f};
  floatx4 acc[2][4], sum[2][4];
#pragma unroll
  for (int i = 0; i < 2; i++)
#pragma unroll
    for (int j = 0; j < 4; j++) { acc[i][j] = zero; sum[i][j] = zero; }

  int srow = tid >> 2, sq = tid & 3;
  const __hip_bfloat16* Ap = A + (size_t)(row0 + srow) * K + sq * 8;
  const __hip_bfloat16* Bp1 = Bt + (size_t)(col0 + srow) * K + sq * 8;
  const __hip_bfloat16* Bp2 = Bt + (size_t)(col0 + 64 + srow) * K + sq * 8;
  bool aok = (row0 + srow) < M;

  uint4 a1 = make_uint4(0, 0, 0, 0);
  if (aok) a1 = *(const uint4*)(Ap);
  uint4 b1 = *(const uint4*)(Bp1);
  uint4 b2 = *(const uint4*)(Bp2);

  for (int k0 = 0; k0 < K; k0 += 32) {
    __syncthreads();
    *(uint4*)&As[srow * 40 + sq * 8] = a1;
    *(uint4*)&Bs[srow * 40 + sq * 8] = b1;
    *(uint4*)&Bs[(64 + srow) * 40 + sq * 8] = b2;
    int kn = k0 + 32;
    if (kn < K) {
      if (aok) a1 = *(const uint4*)(Ap + kn);
      b1 = *(const uint4*)(Bp1 + kn);
      b2 = *(const uint4*)(Bp2 + kn);
    }
    __syncthreads();
    short8 fa[2], fb[4];
#pragma unroll
    for (int i = 0; i < 2; i++)
      fa[i] = *(const short8*)&As[(wr * 32 + i * 16 + l16) * 40 + quad * 8];
#pragma unroll
    for (int i = 0; i < 4; i++)
      fb[i] = *(const short8*)&Bs[(wc * 64 + i * 16 + l16) * 40 + quad * 8];
#pragma unroll
    for (int mi = 0; mi < 2; mi++)
#pragma unroll
      for (int ni = 0; ni < 4; ni++)
        acc[mi][ni] = __builtin_amdgcn_mfma_f32_16x16x32_bf16(fa[mi], fb[ni], acc[mi][ni], 0, 0, 0);
    if (((k0 + 32) & 255) == 0) {  // head boundary: fold elu(acc + b_h)
      int h = k0 >> 8;
#pragma unroll
      for (int mi = 0; mi < 2; mi++)
#pragma unroll
        for (int ni = 0; ni < 4; ni++) {
          int c = col0 + wc * 64 + ni * 16 + l16;
          float bv = bias[h * 256 + c];
#pragma unroll
          for (int reg = 0; reg < 4; reg++) {
            sum[mi][ni][reg] += elu_f(acc[mi][ni][reg] + bv);
            acc[mi][ni][reg] = 0.f;
          }
        }
    }
  }

#pragma unroll
  for (int mi = 0; mi < 2; mi++) {
    int rbase = row0 + wr * 32 + mi * 16 + quad * 4;
#pragma unroll
    for (int ni = 0; ni < 4; ni++) {
      int c = col0 + wc * 64 + ni * 16 + l16;
#pragma unroll
      for (int reg = 0; reg < 4; reg++) {
        int rr = rbase + reg;
        if (rr >= M) continue;
        comb[(size_t)rr * 512 + c] = __float2bfloat16(sum[mi][ni][reg] * 0.125f);
      }
    }
  }
}

// ---------------- attention-vector projection for GAT3 ----------------
__global__ void aproj_k(const float* __restrict__ w_g3, const float* __restrict__ a_s,
                        const float* __restrict__ a_d, float* __restrict__ apj) {
  int idx = blockIdx.x * blockDim.x + threadIdx.x;
  if (idx >= 256 * 16) return;
  int k = idx >> 4, o = idx & 15;
  int h = o >> 1;
  const float* av = (o & 1) ? (a_d + h * 256) : (a_s + h * 256);
  const float* wr = w_g3 + (size_t)k * 2048 + h * 256;
  float s = 0.f;
  for (int c = 0; c < 256; c++) s += wr[c] * av[c];
  apj[idx] = s;
}

__global__ __launch_bounds__(256) void alpha3_k(const __hip_bfloat16* __restrict__ g2,
                                                const float* __restrict__ apj,
                                                float* __restrict__ as_, float* __restrict__ ad_,
                                                int M) {
  int tid = threadIdx.x;
  int nl = tid >> 4, o = tid & 15;
  int n = blockIdx.x * 16 + nl;
  if (n >= M) return;
  const __hip_bfloat16* row = g2 + (size_t)n * 256;
  float s = 0.f;
  for (int c = 0; c < 256; c++) s += __bfloat162float(row[c]) * apj[c * 16 + o];
  if (o & 1) ad_[n * 8 + (o >> 1)] = s;
  else as_[n * 8 + (o >> 1)] = s;
}

__global__ void alpha_small_k(const __hip_bfloat16* __restrict__ hW, const float* __restrict__ a_s,
                              const float* __restrict__ a_d, float* __restrict__ as_,
                              float* __restrict__ ad_, int M) {
  int idx = blockIdx.x * blockDim.x + threadIdx.x;
  if (idx >= M * HEADS) return;
  int h = idx & 7;
  const __hip_bfloat16* row = hW + (size_t)(idx >> 3) * HID + h * 32;
  const float* ws = a_s + h * 32;
  const float* wd = a_d + h * 32;
  float s = 0.f, d = 0.f;
#pragma unroll
  for (int c = 0; c < 32; c++) {
    float v = __bfloat162float(row[c]);
    s += v * ws[c];
    d += v * wd[c];
  }
  as_[idx] = s;
  ad_[idx] = d;
}

// ---------------- edge softmax: unnormalized ex + invden ----------------
__global__ __launch_bounds__(256) void esoft_k(const int* __restrict__ rp,
                                               const int* __restrict__ col,
                                               const float* __restrict__ as_,
                                               const float* __restrict__ ad_,
                                               float* __restrict__ ex,
                                               float* __restrict__ invden, int M) {
  int dst = blockIdx.x * 4 + (threadIdx.x >> 6);
  if (dst >= M) return;
  int lane = threadIdx.x & 63;
  int es = lane >> 3, h = lane & 7;
  int beg = rp[dst], end = rp[dst + 1];
  float adv = ad_[dst * 8 + h];
  float m = -3.4e38f;
  for (int i = beg + es; i < end; i += 8) {
    float e = as_[col[i] * 8 + h] + adv;
    e = e > 0.f ? e : 0.2f * e;
    m = fmaxf(m, e);
  }
  m = fmaxf(m, __shfl_xor(m, 8));
  m = fmaxf(m, __shfl_xor(m, 16));
  m = fmaxf(m, __shfl_xor(m, 32));
  float den = 0.f;
  for (int i = beg + es; i < end; i += 8) {
    float e = as_[col[i] * 8 + h] + adv;
    e = e > 0.f ? e : 0.2f * e;
    float v = __expf(e - m);
    ex[(size_t)i * 8 + h] = v;
    den += v;
  }
  den += __shfl_xor(den, 8);
  den += __shfl_xor(den, 16);
  den += __shfl_xor(den, 32);
  if (es == 0) invden[dst * 8 + h] = 1.f / (den + 1e-16f);
}

// ---------------- weighted aggregate, GAT1/2 ----------------
__global__ __launch_bounds__(64) void aggw_k(const int* __restrict__ rp,
                                             const int* __restrict__ col,
                                             const __hip_bfloat16* __restrict__ hW,
                                             const float* __restrict__ ex,
                                             const float* __restrict__ invden,
                                             const float* __restrict__ bias,
                                             __hip_bfloat16* __restrict__ out) {
  int dst = blockIdx.x;
  int t = threadIdx.x;
  int h = t >> 3, c = t << 2;
  int beg = rp[dst], end = rp[dst + 1];
  float a0 = 0.f, a1 = 0.f, a2 = 0.f, a3 = 0.f;
  for (int i = beg; i < end; i++) {
    int s = col[i];
    float wgt = ex[(size_t)i * 8 + h];
    union { uint2 u; unsigned short us[4]; } uu;
    uu.u = *(const uint2*)(hW + (size_t)s * HID + c);
    a0 += wgt * bf2f(uu.us[0]);
    a1 += wgt * bf2f(uu.us[1]);
    a2 += wgt * bf2f(uu.us[2]);
    a3 += wgt * bf2f(uu.us[3]);
  }
  float inv = invden[dst * 8 + h];
  out[(size_t)dst * HID + c + 0] = __float2bfloat16(elu_f(a0 * inv + bias[c + 0]));
  out[(size_t)dst * HID + c + 1] = __float2bfloat16(elu_f(a1 * inv + bias[c + 1]));
  out[(size_t)dst * HID + c + 2] = __float2bfloat16(elu_f(a2 * inv + bias[c + 2]));
  out[(size_t)dst * HID + c + 3] = __float2bfloat16(elu_f(a3 * inv + bias[c + 3]));
}

// ---------------- GAT3 aggregate: bfloat162-vectorized ----------------
// 128 threads/dst; thread t owns channels (2t, 2t+1), all 8 heads.
__global__ __launch_bounds__(128) void agg3_k(const int* __restrict__ rp,
                                              const int* __restrict__ col,
                                              const __hip_bfloat16* __restrict__ g2,
                                              const float* __restrict__ ex,
                                              const float* __restrict__ invden,
                                              __hip_bfloat16* __restrict__ outA) {
  int dst = blockIdx.x;
  int t = threadIdx.x;
  int beg = rp[dst], end = rp[dst + 1];
  float acc0[8] = {}, acc1[8] = {};
  for (int i = beg; i < end; i++) {
    int s = col[i];
    float4 w0 = *(const float4*)(ex + (size_t)i * 8);
    float4 w1 = *(const float4*)(ex + (size_t)i * 8 + 4);
    union { unsigned int u; unsigned short us[2]; } uu;
    uu.u = *(const unsigned int*)(g2 + (size_t)s * 256 + t * 2);
    float v0 = bf2f(uu.us[0]), v1 = bf2f(uu.us[1]);
    acc0[0] += w0.x * v0; acc0[1] += w0.y * v0; acc0[2] += w0.z * v0; acc0[3] += w0.w * v0;
    acc0[4] += w1.x * v0; acc0[5] += w1.y * v0; acc0[6] += w1.z * v0; acc0[7] += w1.w * v0;
    acc1[0] += w0.x * v1; acc1[1] += w0.y * v1; acc1[2] += w0.z * v1; acc1[3] += w0.w * v1;
    acc1[4] += w1.x * v1; acc1[5] += w1.y * v1; acc1[6] += w1.z * v1; acc1[7] += w1.w * v1;
  }
#pragma unroll
  for (int h = 0; h < 8; h++) {
    float inv = invden[dst * 8 + h];
    unsigned int pack = (unsigned int)f2bfu(acc0[h] * inv) |
                        ((unsigned int)f2bfu(acc1[h] * inv) << 16);
    *(unsigned int*)(outA + (size_t)dst * 2048 + h * 256 + t * 2) = pack;
  }
}

// ---------------- final: logits = hidden @ w_c2 + b_c2 ----------------
__global__ __launch_bounds__(64) void final_k(const float* __restrict__ hidden,
                                              const float* __restrict__ w,
                                              const float* __restrict__ b,
                                              float* __restrict__ out) {
  int n = blockIdx.x;
  int l = threadIdx.x;
  const float* hr = hidden + (size_t)n * HID;
  float a0 = 0.f, a1 = 0.f;
  for (int k = l; k < HID; k += 64) {
    float hv = hr[k];
    a0 += hv * w[k * 2 + 0];
    a1 += hv * w[k * 2 + 1];
  }
  for (int off = 32; off > 0; off >>= 1) {
    a0 += __shfl_down(a0, off);
    a1 += __shfl_down(a1, off);
  }
  if (l == 0) {
    out[n * 2 + 0] = a0 + b[0];
    out[n * 2 + 1] = a1 + b[1];
  }
}

extern "C" void kernel_launch(void* const* d_in, const int* in_sizes, int n_in,
                              void* d_out, int out_size, void* d_ws, size_t ws_size,
                              hipStream_t stream) {
  const float* x      = (const float*)d_in[0];
  const int*   ei     = (const int*)d_in[1];
  const float* w_in   = (const float*)d_in[2];
  const float* b_in   = (const float*)d_in[3];
  const float* w_t1   = (const float*)d_in[4];
  const float* b_t1   = (const float*)d_in[5];
  const float* w_t2   = (const float*)d_in[6];
  const float* b_t2   = (const float*)d_in[7];
  const float* w_g1   = (const float*)d_in[8];
  const float* a_src1 = (const float*)d_in[9];
  const float* a_dst1 = (const float*)d_in[10];
  const float* b_g1   = (const float*)d_in[11];
  const float* w_g2   = (const float*)d_in[12];
  const float* a_src2 = (const float*)d_in[13];
  const float* a_dst2 = (const float*)d_in[14];
  const float* b_g2   = (const float*)d_in[15];
  const float* w_g3   = (const float*)d_in[16];
  const float* a_src3 = (const float*)d_in[17];
  const float* a_dst3 = (const float*)d_in[18];
  const float* b_g3   = (const float*)d_in[19];
  const float* w_c1   = (const float*)d_in[20];
  const float* b_c1   = (const float*)d_in[21];
  const float* w_c2   = (const float*)d_in[22];
  const float* b_c2   = (const float*)d_in[23];
  const int M = in_sizes[0] / FIN;  // 20000
  const int E = in_sizes[1] / 2;    // 120000
  (void)n_in; (void)out_size; (void)ws_size;

  char* wsb = (char*)d_ws;
  size_t off = 0;
  auto alloc = [&](size_t bytes) {
    void* p = wsb + off;
    off = (off + bytes + 255) & ~(size_t)255;
    return p;
  };
  typedef __hip_bfloat16 bf;
  bf* xb     = (bf*)alloc((size_t)M * 256 * 2);
  bf* wtin   = (bf*)alloc(256 * 256 * 2);
  bf* wtpair = (bf*)alloc(512 * 256 * 2);   // [w_t1^T ; w_g1^T] stacked
  bf* wtt2   = (bf*)alloc(256 * 256 * 2);
  bf* wtg2   = (bf*)alloc(256 * 256 * 2);
  bf* wtg3s  = (bf*)alloc(256 * 2048 * 2);  // per-head transposed W3
  bf* wtc1   = (bf*)alloc(256 * 512 * 2);
  bf* actA   = (bf*)alloc((size_t)M * HID * 2);      // h, later g2
  bf* actB   = (bf*)alloc((size_t)M * HID * 2);      // th, later g1
  bf* hW1    = (bf*)alloc((size_t)M * HID * 2);      // hW for GAT1/2
  bf* comb   = (bf*)alloc((size_t)M * 2 * HID * 2);  // [g | t]
  void* hWreg = alloc((size_t)M * 2048 * 2);         // agg3 out bf16; hidden f32
  bf* hWb    = (bf*)hWreg;
  float* hidden = (float*)hWreg;
  float* as_ = (float*)alloc((size_t)M * 8 * 4);
  float* ad_ = (float*)alloc((size_t)M * 8 * 4);
  float* apj = (float*)alloc(256 * 16 * 4);
  float* exw = (float*)alloc((size_t)(E + M) * 8 * 4);
  float* ivd = (float*)alloc((size_t)M * 8 * 4);
  int* deg   = (int*)alloc((size_t)M * 4);
  int* fillc = (int*)alloc((size_t)M * 4);
  int* rp    = (int*)alloc((size_t)(M + 1) * 4);
  int* colA  = (int*)alloc((size_t)(E + M) * 4);

  // ---- conversions ----
  xcvt_k<<<(M * 256 + 255) / 256, 256, 0, stream>>>(x, xb, M);
  dim3 tb(32, 8);
  tcvt_k<<<dim3(8, 8), tb, 0, stream>>>(w_in, wtin, FIN, 256, 256);
  tcvt_k<<<dim3(8, 8), tb, 0, stream>>>(w_t1, wtpair, 256, 256, 256);
  tcvt_k<<<dim3(8, 8), tb, 0, stream>>>(w_g1, wtpair + 256 * 256, 256, 256, 256);
  tcvt_k<<<dim3(8, 8), tb, 0, stream>>>(w_t2, wtt2, 256, 256, 256);
  tcvt_k<<<dim3(8, 8), tb, 0, stream>>>(w_g2, wtg2, 256, 256, 256);
  for (int h = 0; h < 8; h++)  // wtg3s[oc, h*256+c] = w_g3[c, h*256+oc]
    tcvt_k<<<dim3(8, 8), tb, 0, stream>>>(w_g3 + h * 256, wtg3s + h * 256, 256, 2048, 2048);
  tcvt_k<<<dim3(8, 16), tb, 0, stream>>>(w_c1, wtc1, 512, 512, 256);
  aproj_k<<<16, 256, 0, stream>>>(w_g3, a_src3, a_dst3, apj);

  // ---- CSR build ----
  init_deg_k<<<(M + 255) / 256, 256, 0, stream>>>(deg, fillc, M);
  count_k<<<(E + 255) / 256, 256, 0, stream>>>(ei, deg, E);
  scan_k<<<1, 1024, 0, stream>>>(deg, rp, M);
  fill_k<<<(E + M + 255) / 256, 256, 0, stream>>>(ei, rp, fillc, colA, E, M);

  auto gemm = [&](const bf* A, const bf* Bt, const float* bias, float* Cf, bf* Cb,
                  int ldc, int m, int n, int k, int act) {
    dim3 g(n / 128, (m + 63) / 64);
    if (Cb) {
      if (act == 0)      mgemm_k<0, 1><<<g, 256, 0, stream>>>(A, Bt, bias, nullptr, Cb, ldc, m, n, k);
      else if (act == 1) mgemm_k<1, 1><<<g, 256, 0, stream>>>(A, Bt, bias, nullptr, Cb, ldc, m, n, k);
      else               mgemm_k<2, 1><<<g, 256, 0, stream>>>(A, Bt, bias, nullptr, Cb, ldc, m, n, k);
    } else {
      if (act == 0)      mgemm_k<0, 0><<<g, 256, 0, stream>>>(A, Bt, bias, Cf, nullptr, ldc, m, n, k);
      else if (act == 1) mgemm_k<1, 0><<<g, 256, 0, stream>>>(A, Bt, bias, Cf, nullptr, ldc, m, n, k);
      else               mgemm_k<2, 0><<<g, 256, 0, stream>>>(A, Bt, bias, Cf, nullptr, ldc, m, n, k);
    }
  };
  int eg = (M + 3) / 4;
  int mg = (M + 63) / 64;

  // h = elu(x @ w_in + b_in) -> actA
  gemm(xb, wtin, b_in, nullptr, actA, HID, M, HID, 256, 2);
  // dual: th=relu(h@w_t1+b_t1) -> actB ; hW1 = h@w_g1 -> hW1
  mgemm_dual_k<<<dim3(4, mg), 256, 0, stream>>>(actA, wtpair, b_t1, actB, hW1, M);
  // t = th @ w_t2 + b_t2 -> comb[:,256:512]
  gemm(actB, wtt2, b_t2, nullptr, comb + HID, 2 * HID, M, HID, 256, 0);

  // ---- GAT 1 ----
  alpha_small_k<<<(M * 8 + 63) / 64, 64, 0, stream>>>(hW1, a_src1, a_dst1, as_, ad_, M);
  esoft_k<<<eg, 256, 0, stream>>>(rp, colA, as_, ad_, exw, ivd, M);
  aggw_k<<<M, 64, 0, stream>>>(rp, colA, hW1, exw, ivd, b_g1, actB);  // g1

  // ---- GAT 2 ----
  gemm(actB, wtg2, nullptr, nullptr, hW1, HID, M, HID, 256, 0);
  alpha_small_k<<<(M * 8 + 63) / 64, 64, 0, stream>>>(hW1, a_src2, a_dst2, as_, ad_, M);
  esoft_k<<<eg, 256, 0, stream>>>(rp, colA, as_, ad_, exw, ivd, M);
  aggw_k<<<M, 64, 0, stream>>>(rp, colA, hW1, exw, ivd, b_g2, actA);  // g2

  // ---- GAT 3 ----
  alpha3_k<<<(M + 15) / 16, 256, 0, stream>>>(actA, apj, as_, ad_, M);
  esoft_k<<<eg, 256, 0, stream>>>(rp, colA, as_, ad_, exw, ivd, M);
  agg3_k<<<M, 128, 0, stream>>>(rp, colA, actA, exw, ivd, hWb);
  mgemm3_k<<<dim3(2, mg), 256, 0, stream>>>(hWb, wtg3s, b_g3, comb, M);

  // ---- classifier ----
  gemm(comb, wtc1, b_c1, hidden, nullptr, HID, M, HID, 512, 1);
  final_k<<<M, 64, 0, stream>>>(hidden, w_c2, b_c2, (float*)d_out);
}